// Round 4
// baseline (1855.378 us; speedup 1.0000x reference)
//
#include <hip/hip_runtime.h>
#include <hip/hip_bf16.h>
#include <math.h>

// HGAT: 2-layer hypergraph attention. N nodes, M hyperedges, E incidence edges, D=128.
// R4: (1) MFMA bf16 fc (was VALU, 1 block/CU latency-bound at 130us); (2) bucketed
// two-pass CSR scatter (was 107MB write amplification from random 4B writes, 131us);
// (3) fused 3-way histogram. segA/segB/softmax path unchanged from R3 (bf16 rows).

typedef unsigned int u32;
typedef unsigned short u16;
typedef u16 u16x8 __attribute__((ext_vector_type(8)));
typedef short bf16x8 __attribute__((ext_vector_type(8)));
typedef float f32x4 __attribute__((ext_vector_type(4)));

#define NCONST 100000
#define MCONST 20000
#define ECONST 1600000

__device__ __forceinline__ u16 f2bf(float f) {  // RNE
  u32 u = __float_as_uint(f);
  u += 0x7FFFu + ((u >> 16) & 1u);
  return (u16)(u >> 16);
}
__device__ __forceinline__ float bf2f(u16 b) {
  return __uint_as_float(((u32)b) << 16);
}

// ---------------- CSR build ----------------
// fused histogram: in_dst -> ca, has_dst -> cb, in_src -> cc
__global__ void k_hist3(const int* __restrict__ a, const int* __restrict__ b,
                        const int* __restrict__ c, int n, int* __restrict__ ca,
                        int* __restrict__ cb, int* __restrict__ cc) {
  int i = blockIdx.x * blockDim.x + threadIdx.x;
  int st = gridDim.x * blockDim.x;
  for (; i < n; i += st) {
    atomicAdd(&ca[a[i]], 1);
    atomicAdd(&cb[b[i]], 1);
    atomicAdd(&cc[c[i]], 1);
  }
}

__global__ void k_scan1(const int* __restrict__ cnt, int n, int* __restrict__ off,
                        int* __restrict__ bsum) {
  __shared__ int sd[256];
  int t = threadIdx.x;
  int base = blockIdx.x * 1024 + t * 4;
  int v0 = (base + 0 < n) ? cnt[base + 0] : 0;
  int v1 = (base + 1 < n) ? cnt[base + 1] : 0;
  int v2 = (base + 2 < n) ? cnt[base + 2] : 0;
  int v3 = (base + 3 < n) ? cnt[base + 3] : 0;
  v1 += v0; v2 += v1; v3 += v2;
  int tot = v3;
  sd[t] = tot;
  __syncthreads();
  for (int o = 1; o < 256; o <<= 1) {
    int x = (t >= o) ? sd[t - o] : 0;
    __syncthreads();
    sd[t] += x;
    __syncthreads();
  }
  int excl = sd[t] - tot;
  if (base + 0 < n) off[base + 1] = v0 + excl;
  if (base + 1 < n) off[base + 2] = v1 + excl;
  if (base + 2 < n) off[base + 3] = v2 + excl;
  if (base + 3 < n) off[base + 4] = v3 + excl;
  if (t == 255) bsum[blockIdx.x] = sd[255];
}

__global__ void k_scan2(int* __restrict__ bsum, int nb) {
  __shared__ int sd[256];
  int t = threadIdx.x;
  int v = (t < nb) ? bsum[t] : 0;
  sd[t] = v;
  __syncthreads();
  for (int o = 1; o < 256; o <<= 1) {
    int x = (t >= o) ? sd[t - o] : 0;
    __syncthreads();
    sd[t] += x;
    __syncthreads();
  }
  if (t < nb) bsum[t] = sd[t] - v;  // exclusive
}

__global__ void k_scan3(int* __restrict__ off, int n, const int* __restrict__ bsum) {
  int i = blockIdx.x * blockDim.x + threadIdx.x;
  int st = gridDim.x * blockDim.x;
  if (blockIdx.x == 0 && threadIdx.x == 0) off[0] = 0;
  for (; i < n; i += st) off[i + 1] += bsum[i >> 10];
}

// bucketed scatter: bucket b region in pairs/csrc space is [off[b<<sh], off[(b+1)<<sh])
__global__ void k_binit(const int* __restrict__ off, int segs, int shift, int nb,
                        int* __restrict__ bcur) {
  int b = blockIdx.x * blockDim.x + threadIdx.x;
  if (b < nb) bcur[b] = off[min(b << shift, segs)];
}

__global__ void k_part(const int* __restrict__ dst, const int* __restrict__ srcv, int n,
                       int shift, int* __restrict__ bcur, int2* __restrict__ ebuf) {
  int i = blockIdx.x * blockDim.x + threadIdx.x;
  int st = gridDim.x * blockDim.x;
  for (; i < n; i += st) {
    int d = dst[i], s = srcv[i];
    int pos = atomicAdd(&bcur[d >> shift], 1);
    ebuf[pos] = make_int2(d, s);
  }
}

__global__ void k_final(const int* __restrict__ off, int segs, int shift,
                        const int2* __restrict__ ebuf, int* __restrict__ cur,
                        int* __restrict__ csrc) {
  int b = blockIdx.x;
  int start = off[min(b << shift, segs)];
  int end = off[min((b + 1) << shift, segs)];
  for (int i = start + threadIdx.x; i < end; i += blockDim.x) {
    int2 p = ebuf[i];
    int pos = off[p.x] + atomicAdd(&cur[p.x], 1);
    csrc[pos] = p.y;
  }
}

// ---------------- FC: h = x@W + b (bf16 out), na = h@an  [MFMA 16x16x32 bf16] ------------
// block = 256 thr = 4 waves; wave owns 32 rows x 128 cols; K=128.
// LDS: WT[j][k] bf16, row stride 136 (2-way bank alias = free); reused as epilogue staging.
__global__ __launch_bounds__(256, 2) void k_fc(
    const float* __restrict__ x, const float* __restrict__ W,
    const float* __restrict__ bias, const float* __restrict__ an,
    u16* __restrict__ h, float* __restrict__ na, int nrows) {
  __shared__ __align__(16) u16 sWT[128 * 136];
  int tid = threadIdx.x;
  int lane = tid & 63, w = tid >> 6;
  int cl = lane & 15, qg = lane >> 4;

  // stage WT = W^T bf16 (W is [k][j] row-major fp32)
  for (int i = tid * 4; i < 16384; i += 1024) {
    float4 v = *(const float4*)(W + i);
    int k = i >> 7, j = i & 127;
    sWT[(j + 0) * 136 + k] = f2bf(v.x);
    sWT[(j + 1) * 136 + k] = f2bf(v.y);
    sWT[(j + 2) * 136 + k] = f2bf(v.z);
    sWT[(j + 3) * 136 + k] = f2bf(v.w);
  }

  float anv[8], bv[8];
#pragma unroll
  for (int t = 0; t < 8; ++t) {
    anv[t] = an[t * 16 + cl];
    bv[t] = bias[t * 16 + cl];
  }

  // A fragments: rows rbase..rbase+31, fp32 -> bf16 in-register
  int rbase = blockIdx.x * 128 + w * 32;
  bf16x8 afr[2][4];
#pragma unroll
  for (int g = 0; g < 2; ++g) {
    int r = rbase + g * 16 + cl;
    int rc = min(r, nrows - 1);
    const float* xp = x + (size_t)rc * 128 + qg * 8;
#pragma unroll
    for (int s = 0; s < 4; ++s) {
      float4 u0 = *(const float4*)(xp + s * 32);
      float4 u1 = *(const float4*)(xp + s * 32 + 4);
      bf16x8 a;
      a[0] = (short)f2bf(u0.x); a[1] = (short)f2bf(u0.y);
      a[2] = (short)f2bf(u0.z); a[3] = (short)f2bf(u0.w);
      a[4] = (short)f2bf(u1.x); a[5] = (short)f2bf(u1.y);
      a[6] = (short)f2bf(u1.z); a[7] = (short)f2bf(u1.w);
      afr[g][s] = a;
    }
  }
  __syncthreads();

  f32x4 acc[2][8];
#pragma unroll
  for (int g = 0; g < 2; ++g)
#pragma unroll
    for (int t = 0; t < 8; ++t) {
      acc[g][t][0] = 0.f; acc[g][t][1] = 0.f; acc[g][t][2] = 0.f; acc[g][t][3] = 0.f;
    }

#pragma unroll
  for (int t = 0; t < 8; ++t) {
    bf16x8 bfrg[4];
    const u16* bp = sWT + (t * 16 + cl) * 136 + qg * 8;
#pragma unroll
    for (int s = 0; s < 4; ++s) bfrg[s] = *(const bf16x8*)(bp + s * 32);
#pragma unroll
    for (int s = 0; s < 4; ++s) {
#pragma unroll
      for (int g = 0; g < 2; ++g)
        acc[g][t] = __builtin_amdgcn_mfma_f32_16x16x32_bf16(afr[g][s], bfrg[s], acc[g][t],
                                                            0, 0, 0);
    }
  }

  // na partials: D layout col = cl, row = qg*4 + reg (+ g*16)
  float pa[2][4];
#pragma unroll
  for (int g = 0; g < 2; ++g)
#pragma unroll
    for (int reg = 0; reg < 4; ++reg) pa[g][reg] = 0.f;
#pragma unroll
  for (int g = 0; g < 2; ++g)
#pragma unroll
    for (int t = 0; t < 8; ++t)
#pragma unroll
      for (int reg = 0; reg < 4; ++reg)
        pa[g][reg] = fmaf(acc[g][t][reg] + bv[t], anv[t], pa[g][reg]);
#pragma unroll
  for (int g = 0; g < 2; ++g)
#pragma unroll
    for (int reg = 0; reg < 4; ++reg) {
      float v = pa[g][reg];
      v += __shfl_xor(v, 1, 64);
      v += __shfl_xor(v, 2, 64);
      v += __shfl_xor(v, 4, 64);
      v += __shfl_xor(v, 8, 64);
      pa[g][reg] = v;
    }
  if (cl == 0) {
#pragma unroll
    for (int g = 0; g < 2; ++g)
#pragma unroll
      for (int reg = 0; reg < 4; ++reg) {
        int r = rbase + g * 16 + qg * 4 + reg;
        if (r < nrows) na[r] = pa[g][reg];
      }
  }

  // epilogue: stage h tile (bf16) through LDS (reuse sWT), then coalesced store
  __syncthreads();
  u16* st = sWT + w * 32 * 136;
#pragma unroll
  for (int g = 0; g < 2; ++g)
#pragma unroll
    for (int t = 0; t < 8; ++t)
#pragma unroll
      for (int reg = 0; reg < 4; ++reg)
        st[(g * 16 + qg * 4 + reg) * 136 + t * 16 + cl] = f2bf(acc[g][t][reg] + bv[t]);
#pragma unroll
  for (int it = 0; it < 8; ++it) {
    int idx = it * 64 + lane;  // 32 rows x 16 chunks of 8 bf16
    int row = idx >> 4, c = idx & 15;
    u16x8 v = *(const u16x8*)(st + row * 136 + c * 8);
    int r = rbase + row;
    if (r < nrows) *(u16x8*)(h + (size_t)r * 128 + c * 8) = v;
  }
}

// ---------------- online softmax reductions ----------------
__device__ __forceinline__ void merge_write(float m, float s, float2* __restrict__ pairs) {
  for (int o = 1; o < 64; o <<= 1) {
    float om = __shfl_xor(m, o, 64), os = __shfl_xor(s, o, 64);
    float nm = fmaxf(m, om);
    s = s * __expf(m - nm) + os * __expf(om - nm);
    m = nm;
  }
  __shared__ float sm[4], ss[4];
  int t = threadIdx.x;
  if ((t & 63) == 0) { sm[t >> 6] = m; ss[t >> 6] = s; }
  __syncthreads();
  if (t == 0) {
    for (int k = 1; k < 4; ++k) {
      float nm = fmaxf(m, sm[k]);
      s = s * __expf(m - nm) + ss[k] * __expf(sm[k] - nm);
      m = nm;
    }
    pairs[blockIdx.x] = make_float2(m, s);
  }
}

// softmax1 factorized over nodes: max over deg>0 nodes; sum = sum deg*exp(na-m)
__global__ void k_sm1(const float* __restrict__ na, const int* __restrict__ deg, int n,
                      float2* __restrict__ pairs) {
  float m = -1e30f, s = 0.f;
  int i = blockIdx.x * blockDim.x + threadIdx.x;
  int st = gridDim.x * blockDim.x;
  for (; i < n; i += st) {
    int d = deg[i];
    if (d > 0) {
      float xv = na[i];
      if (xv > m) { s *= __expf(m - xv); m = xv; }
      s += (float)d * __expf(xv - m);
    }
  }
  merge_write(m, s, pairs);
}

// softmax2 single online pass over E
__global__ void k_sm2(const float* __restrict__ ea, const float* __restrict__ na,
                      const int* __restrict__ hs, const int* __restrict__ hd, int n,
                      float2* __restrict__ pairs) {
  float m = -1e30f, s = 0.f;
  int i = blockIdx.x * blockDim.x + threadIdx.x;
  int st = gridDim.x * blockDim.x;
  for (; i < n; i += st) {
    float xv = ea[hs[i]] + na[hd[i]];
    if (xv > m) { s *= __expf(m - xv); m = xv; }
    s += __expf(xv - m);
  }
  merge_write(m, s, pairs);
}

__global__ void k_smfin(const float2* __restrict__ pairs, int nb, float* __restrict__ out) {
  int t = threadIdx.x;
  float m = -1e30f, s = 0.f;
  for (int i = t; i < nb; i += 256) {
    float2 pr = pairs[i];
    float nm = fmaxf(m, pr.x);
    s = s * __expf(m - nm) + pr.y * __expf(pr.x - nm);
    m = nm;
  }
  for (int o = 1; o < 64; o <<= 1) {
    float om = __shfl_xor(m, o, 64), os = __shfl_xor(s, o, 64);
    float nm = fmaxf(m, om);
    s = s * __expf(m - nm) + os * __expf(om - nm);
    m = nm;
  }
  __shared__ float sm[4], ss[4];
  if ((t & 63) == 0) { sm[t >> 6] = m; ss[t >> 6] = s; }
  __syncthreads();
  if (t == 0) {
    for (int k = 1; k < 4; ++k) {
      float nm = fmaxf(m, sm[k]);
      s = s * __expf(m - nm) + ss[k] * __expf(sm[k] - nm);
      m = nm;
    }
    out[0] = m;
    out[1] = s;
  }
}

__global__ void k_wnode(const float* __restrict__ na, const float* __restrict__ sc,
                        float* __restrict__ w, int n) {
  float mx = sc[0];
  float iz = 1.0f / sc[1];
  int i = blockIdx.x * blockDim.x + threadIdx.x;
  if (i < n) w[i] = __expf(na[i] - mx) * iz;
}

__global__ void k_pe(const float* __restrict__ ea, const float* __restrict__ sc,
                     float* __restrict__ pe, int m) {
  float mx = sc[0];
  float iz = 1.0f / sc[1];
  int i = blockIdx.x * blockDim.x + threadIdx.x;
  if (i < m) pe[i] = __expf(ea[i] - mx) * iz;
}

// ---------------- segment sums (one wave/segment, 16B/lane, 4 edges/iter) ----------------
__global__ __launch_bounds__(256) void k_segA(
    const u16* __restrict__ h, const float* __restrict__ w,
    const int* __restrict__ csrc, const int* __restrict__ off,
    const float* __restrict__ ae, u16* __restrict__ he,
    float* __restrict__ ea, int m_count) {
  int wid = (blockIdx.x << 2) + (threadIdx.x >> 6);
  if (wid >= m_count) return;
  int lane = threadIdx.x & 63;
  int sub = lane >> 4, cl = lane & 15;
  int s = off[wid], t = off[wid + 1];
  float ax[8];
#pragma unroll
  for (int j = 0; j < 8; ++j) ax[j] = 0.f;
  for (int i = s + sub; i < t; i += 4) {
    int sr = csrc[i];
    float ww = w[sr];
    u16x8 v = *(const u16x8*)(h + (size_t)sr * 128 + cl * 8);
#pragma unroll
    for (int j = 0; j < 8; ++j) ax[j] = fmaf(ww, bf2f(v[j]), ax[j]);
  }
#pragma unroll
  for (int j = 0; j < 8; ++j) {
    ax[j] += __shfl_xor(ax[j], 16, 64);
    ax[j] += __shfl_xor(ax[j], 32, 64);
  }
  float4 a0 = *(const float4*)(ae + cl * 8);
  float4 a1 = *(const float4*)(ae + cl * 8 + 4);
  float pa = ax[0] * a0.x + ax[1] * a0.y + ax[2] * a0.z + ax[3] * a0.w +
             ax[4] * a1.x + ax[5] * a1.y + ax[6] * a1.z + ax[7] * a1.w;
  pa += __shfl_xor(pa, 1, 64);
  pa += __shfl_xor(pa, 2, 64);
  pa += __shfl_xor(pa, 4, 64);
  pa += __shfl_xor(pa, 8, 64);
  if (sub == 0) {
    u16x8 o;
#pragma unroll
    for (int j = 0; j < 8; ++j) o[j] = f2bf(ax[j]);
    *(u16x8*)(he + (size_t)wid * 128 + cl * 8) = o;
    if (cl == 0) ea[wid] = pa;
  }
}

__global__ __launch_bounds__(256) void k_segB(
    const u16* __restrict__ he, const float* __restrict__ pe,
    const float* __restrict__ na, const int* __restrict__ csrc,
    const int* __restrict__ off, float* __restrict__ y, int n_count, int relu) {
  int wid = (blockIdx.x << 2) + (threadIdx.x >> 6);
  if (wid >= n_count) return;
  int lane = threadIdx.x & 63;
  int sub = lane >> 4, cl = lane & 15;
  float rf = __expf(na[wid]);  // exp(ea+na-mx)/Z = pe[sr]*exp(na)
  int s = off[wid], t = off[wid + 1];
  float ax[8];
#pragma unroll
  for (int j = 0; j < 8; ++j) ax[j] = 0.f;
  for (int i = s + sub; i < t; i += 4) {
    int sr = csrc[i];
    float c = pe[sr];
    u16x8 v = *(const u16x8*)(he + (size_t)sr * 128 + cl * 8);
#pragma unroll
    for (int j = 0; j < 8; ++j) ax[j] = fmaf(c, bf2f(v[j]), ax[j]);
  }
#pragma unroll
  for (int j = 0; j < 8; ++j) {
    ax[j] += __shfl_xor(ax[j], 16, 64);
    ax[j] += __shfl_xor(ax[j], 32, 64);
    ax[j] *= rf;
    if (relu) ax[j] = fmaxf(ax[j], 0.f);
  }
  if (sub == 0) {
    float4 A = make_float4(ax[0], ax[1], ax[2], ax[3]);
    float4 B = make_float4(ax[4], ax[5], ax[6], ax[7]);
    *(float4*)(y + (size_t)wid * 128 + cl * 8) = A;
    *(float4*)(y + (size_t)wid * 128 + cl * 8 + 4) = B;
  }
}

// ---------------- host ----------------
extern "C" void kernel_launch(void* const* d_in, const int* in_sizes, int n_in,
                              void* d_out, int out_size, void* d_ws, size_t ws_size,
                              hipStream_t stream) {
  const int N = NCONST, M = MCONST, E = ECONST;
  const float* x = (const float*)d_in[0];
  const int* in_src = (const int*)d_in[1];
  const int* in_dst = (const int*)d_in[2];
  const int* has_src = (const int*)d_in[3];
  const int* has_dst = (const int*)d_in[4];
  const float* W1 = (const float*)d_in[5];
  const float* b1 = (const float*)d_in[6];
  const float* an1 = (const float*)d_in[7];
  const float* ae1 = (const float*)d_in[8];
  const float* W2 = (const float*)d_in[9];
  const float* b2 = (const float*)d_in[10];
  const float* an2 = (const float*)d_in[11];
  const float* ae2 = (const float*)d_in[12];

  char* p = (char*)d_ws;
  auto alloc = [&](size_t bytes) {
    char* q = p;
    p += (bytes + 255) & ~(size_t)255;
    return q;
  };
  u16* h = (u16*)alloc((size_t)N * 128 * 2);
  u16* he = (u16*)alloc((size_t)M * 128 * 2);
  float* na = (float*)alloc((size_t)N * 4);
  float* ea = (float*)alloc((size_t)M * 4);
  float* wn = (float*)alloc((size_t)N * 4);
  float* pe = (float*)alloc((size_t)M * 4);
  int* off_in = (int*)alloc((size_t)(M + 1) * 4);
  int* off_has = (int*)alloc((size_t)(N + 1) * 4);
  int* csrc_in = (int*)alloc((size_t)E * 4);
  int* csrc_has = (int*)alloc((size_t)E * 4);
  int2* ebuf = (int2*)alloc((size_t)E * 8);
  int* bsum = (int*)alloc(256 * 4);
  int* bcur = (int*)alloc(512 * 4);
  float2* pairs = (float2*)alloc(256 * 8);
  float* scal = (float*)alloc(64);
  char* zbase = p;
  int* cnt_in = (int*)alloc((size_t)M * 4);
  int* cur_in = (int*)alloc((size_t)M * 4);
  int* cnt_has = (int*)alloc((size_t)N * 4);
  int* cur_has = (int*)alloc((size_t)N * 4);
  int* deg_src = (int*)alloc((size_t)N * 4);
  size_t zbytes = (size_t)(p - zbase);
  if ((size_t)(p - (char*)d_ws) > ws_size) return;  // insufficient workspace

  hipMemsetAsync(zbase, 0, zbytes, stream);

  // CSR build (shared by both layers)
  k_hist3<<<1024, 256, 0, stream>>>(in_dst, has_dst, in_src, E, cnt_in, cnt_has, deg_src);
  int nb_in = (M + 1023) / 1024;
  k_scan1<<<nb_in, 256, 0, stream>>>(cnt_in, M, off_in, bsum);
  k_scan2<<<1, 256, 0, stream>>>(bsum, nb_in);
  k_scan3<<<256, 256, 0, stream>>>(off_in, M, bsum);
  int nb_has = (N + 1023) / 1024;
  k_scan1<<<nb_has, 256, 0, stream>>>(cnt_has, N, off_has, bsum);
  k_scan2<<<1, 256, 0, stream>>>(bsum, nb_has);
  k_scan3<<<512, 256, 0, stream>>>(off_has, N, bsum);

  // bucketed scatter: in (shift 6, 313 buckets), has (shift 8, 391 buckets)
  const int SH_IN = 6, NB_IN = (MCONST + 63) >> 6;
  const int SH_HAS = 8, NB_HAS = (NCONST + 255) >> 8;
  k_binit<<<2, 256, 0, stream>>>(off_in, M, SH_IN, NB_IN, bcur);
  k_part<<<1024, 256, 0, stream>>>(in_dst, in_src, E, SH_IN, bcur, ebuf);
  k_final<<<NB_IN, 256, 0, stream>>>(off_in, M, SH_IN, ebuf, cur_in, csrc_in);
  k_binit<<<2, 256, 0, stream>>>(off_has, N, SH_HAS, NB_HAS, bcur);
  k_part<<<1024, 256, 0, stream>>>(has_dst, has_src, E, SH_HAS, bcur, ebuf);
  k_final<<<NB_HAS, 256, 0, stream>>>(off_has, N, SH_HAS, ebuf, cur_has, csrc_has);

  auto layer = [&](const float* xin, const float* W, const float* b, const float* an_,
                   const float* ae_, float* yout, int relu) {
    k_fc<<<(N + 127) / 128, 256, 0, stream>>>(xin, W, b, an_, h, na, N);
    k_sm1<<<256, 256, 0, stream>>>(na, deg_src, N, pairs);
    k_smfin<<<1, 256, 0, stream>>>(pairs, 256, scal);
    k_wnode<<<(N + 255) / 256, 256, 0, stream>>>(na, scal, wn, N);
    k_segA<<<(M + 3) / 4, 256, 0, stream>>>(h, wn, csrc_in, off_in, ae_, he, ea, M);
    k_sm2<<<256, 256, 0, stream>>>(ea, na, has_src, has_dst, E, pairs);
    k_smfin<<<1, 256, 0, stream>>>(pairs, 256, scal + 2);
    k_pe<<<(M + 255) / 256, 256, 0, stream>>>(ea, scal + 2, pe, M);
    k_segB<<<(N + 3) / 4, 256, 0, stream>>>(he, pe, na, csrc_has, off_has, yout, N, relu);
  };

  layer(x, W1, b1, an1, ae1, (float*)d_out, 1);
  layer((const float*)d_out, W2, b2, an2, ae2, (float*)d_out, 0);
}

// Round 6
// 837.377 us; speedup vs baseline: 2.2157x; 2.2157x over previous
//
#include <hip/hip_runtime.h>
#include <hip/hip_bf16.h>
#include <math.h>

// HGAT: 2-layer hypergraph attention. N nodes, M hyperedges, E incidence edges, D=128.
// R6 == R5 resubmit (container died before benching R5).
// R5: scatter redone after R4's contention disaster (313 buckets x 5000 same-addr atomic
// chain @127ns = 637us). Now: in shift=1 (10000 buckets, 160/addr), has shift=2 (25000
// buckets, 64/addr); ebuf packed to 4B ((dloc<<20)|src); pass-2 slotting is atomic-free
// (one wave/bucket, ballot+popcount rank per segment). MFMA fc + bf16 rows from R4.

typedef unsigned int u32;
typedef unsigned short u16;
typedef u16 u16x8 __attribute__((ext_vector_type(8)));
typedef short bf16x8 __attribute__((ext_vector_type(8)));
typedef float f32x4 __attribute__((ext_vector_type(4)));

#define NCONST 100000
#define MCONST 20000
#define ECONST 1600000

__device__ __forceinline__ u16 f2bf(float f) {  // RNE
  u32 u = __float_as_uint(f);
  u += 0x7FFFu + ((u >> 16) & 1u);
  return (u16)(u >> 16);
}
__device__ __forceinline__ float bf2f(u16 b) {
  return __uint_as_float(((u32)b) << 16);
}

// ---------------- CSR build ----------------
// fused histogram: in_dst -> ca, has_dst -> cb, in_src -> cc
__global__ void k_hist3(const int* __restrict__ a, const int* __restrict__ b,
                        const int* __restrict__ c, int n, int* __restrict__ ca,
                        int* __restrict__ cb, int* __restrict__ cc) {
  int i = blockIdx.x * blockDim.x + threadIdx.x;
  int st = gridDim.x * blockDim.x;
  for (; i < n; i += st) {
    atomicAdd(&ca[a[i]], 1);
    atomicAdd(&cb[b[i]], 1);
    atomicAdd(&cc[c[i]], 1);
  }
}

__global__ void k_scan1(const int* __restrict__ cnt, int n, int* __restrict__ off,
                        int* __restrict__ bsum) {
  __shared__ int sd[256];
  int t = threadIdx.x;
  int base = blockIdx.x * 1024 + t * 4;
  int v0 = (base + 0 < n) ? cnt[base + 0] : 0;
  int v1 = (base + 1 < n) ? cnt[base + 1] : 0;
  int v2 = (base + 2 < n) ? cnt[base + 2] : 0;
  int v3 = (base + 3 < n) ? cnt[base + 3] : 0;
  v1 += v0; v2 += v1; v3 += v2;
  int tot = v3;
  sd[t] = tot;
  __syncthreads();
  for (int o = 1; o < 256; o <<= 1) {
    int x = (t >= o) ? sd[t - o] : 0;
    __syncthreads();
    sd[t] += x;
    __syncthreads();
  }
  int excl = sd[t] - tot;
  if (base + 0 < n) off[base + 1] = v0 + excl;
  if (base + 1 < n) off[base + 2] = v1 + excl;
  if (base + 2 < n) off[base + 3] = v2 + excl;
  if (base + 3 < n) off[base + 4] = v3 + excl;
  if (t == 255) bsum[blockIdx.x] = sd[255];
}

__global__ void k_scan2(int* __restrict__ bsum, int nb) {
  __shared__ int sd[256];
  int t = threadIdx.x;
  int v = (t < nb) ? bsum[t] : 0;
  sd[t] = v;
  __syncthreads();
  for (int o = 1; o < 256; o <<= 1) {
    int x = (t >= o) ? sd[t - o] : 0;
    __syncthreads();
    sd[t] += x;
    __syncthreads();
  }
  if (t < nb) bsum[t] = sd[t] - v;  // exclusive
}

__global__ void k_scan3(int* __restrict__ off, int n, const int* __restrict__ bsum) {
  int i = blockIdx.x * blockDim.x + threadIdx.x;
  int st = gridDim.x * blockDim.x;
  if (blockIdx.x == 0 && threadIdx.x == 0) off[0] = 0;
  for (; i < n; i += st) off[i + 1] += bsum[i >> 10];
}

// bucketed scatter pass 1: claim slot in bucket region, write packed (dloc<<20)|src
__global__ void k_binit(const int* __restrict__ off, int segs, int shift, int nb,
                        int* __restrict__ bcur) {
  int b = blockIdx.x * blockDim.x + threadIdx.x;
  if (b < nb) bcur[b] = off[min(b << shift, segs)];
}

__global__ void k_part(const int* __restrict__ dst, const int* __restrict__ srcv, int n,
                       int shift, int* __restrict__ bcur, int* __restrict__ ebuf) {
  int i = blockIdx.x * blockDim.x + threadIdx.x;
  int st = gridDim.x * blockDim.x;
  int msk = (1 << shift) - 1;
  for (; i < n; i += st) {
    int d = dst[i], s = srcv[i];
    int pos = atomicAdd(&bcur[d >> shift], 1);
    ebuf[pos] = ((d & msk) << 20) | s;
  }
}

// pass 2: one wave per bucket; within-bucket slotting by ballot rank (no atomics)
template <int SHIFT>
__global__ __launch_bounds__(64) void k_final(const int* __restrict__ off, int segs,
                                              const int* __restrict__ ebuf,
                                              int* __restrict__ csrc) {
  const int NSEG = 1 << SHIFT;
  int b = blockIdx.x;
  int seg0 = b << SHIFT;
  if (seg0 >= segs) return;
  int segN = min(seg0 + NSEG, segs);
  int start = off[seg0], end = off[segN];
  int lane = threadIdx.x;
  unsigned long long below = (1ull << lane) - 1;
  int cnt[NSEG];
#pragma unroll
  for (int s = 0; s < NSEG; ++s) cnt[s] = 0;
  for (int base = start; base < end; base += 64) {
    int i = base + lane;
    int v = (i < end) ? ebuf[i] : -1;
    int dloc = v >> 20;  // -1 for inactive lanes, never matches s
    int src = v & 0xFFFFF;
#pragma unroll
    for (int s = 0; s < NSEG; ++s) {
      unsigned long long mask = __ballot(dloc == s);
      if (dloc == s) {
        int rank = __popcll(mask & below);
        csrc[off[seg0 + s] + cnt[s] + rank] = src;
      }
      cnt[s] += __popcll(mask);
    }
  }
}

// ---------------- FC: h = x@W + b (bf16 out), na = h@an  [MFMA 16x16x32 bf16] ------------
// block = 256 thr = 4 waves; wave owns 32 rows x 128 cols; K=128.
// LDS: WT[j][k] bf16, row stride 136 (2-way bank alias = free); reused as epilogue staging.
__global__ __launch_bounds__(256, 2) void k_fc(
    const float* __restrict__ x, const float* __restrict__ W,
    const float* __restrict__ bias, const float* __restrict__ an,
    u16* __restrict__ h, float* __restrict__ na, int nrows) {
  __shared__ __align__(16) u16 sWT[128 * 136];
  int tid = threadIdx.x;
  int lane = tid & 63, w = tid >> 6;
  int cl = lane & 15, qg = lane >> 4;

  // stage WT = W^T bf16 (W is [k][j] row-major fp32)
  for (int i = tid * 4; i < 16384; i += 1024) {
    float4 v = *(const float4*)(W + i);
    int k = i >> 7, j = i & 127;
    sWT[(j + 0) * 136 + k] = f2bf(v.x);
    sWT[(j + 1) * 136 + k] = f2bf(v.y);
    sWT[(j + 2) * 136 + k] = f2bf(v.z);
    sWT[(j + 3) * 136 + k] = f2bf(v.w);
  }

  float anv[8], bv[8];
#pragma unroll
  for (int t = 0; t < 8; ++t) {
    anv[t] = an[t * 16 + cl];
    bv[t] = bias[t * 16 + cl];
  }

  // A fragments: rows rbase..rbase+31, fp32 -> bf16 in-register
  int rbase = blockIdx.x * 128 + w * 32;
  bf16x8 afr[2][4];
#pragma unroll
  for (int g = 0; g < 2; ++g) {
    int r = rbase + g * 16 + cl;
    int rc = min(r, nrows - 1);
    const float* xp = x + (size_t)rc * 128 + qg * 8;
#pragma unroll
    for (int s = 0; s < 4; ++s) {
      float4 u0 = *(const float4*)(xp + s * 32);
      float4 u1 = *(const float4*)(xp + s * 32 + 4);
      bf16x8 a;
      a[0] = (short)f2bf(u0.x); a[1] = (short)f2bf(u0.y);
      a[2] = (short)f2bf(u0.z); a[3] = (short)f2bf(u0.w);
      a[4] = (short)f2bf(u1.x); a[5] = (short)f2bf(u1.y);
      a[6] = (short)f2bf(u1.z); a[7] = (short)f2bf(u1.w);
      afr[g][s] = a;
    }
  }
  __syncthreads();

  f32x4 acc[2][8];
#pragma unroll
  for (int g = 0; g < 2; ++g)
#pragma unroll
    for (int t = 0; t < 8; ++t) {
      acc[g][t][0] = 0.f; acc[g][t][1] = 0.f; acc[g][t][2] = 0.f; acc[g][t][3] = 0.f;
    }

#pragma unroll
  for (int t = 0; t < 8; ++t) {
    bf16x8 bfrg[4];
    const u16* bp = sWT + (t * 16 + cl) * 136 + qg * 8;
#pragma unroll
    for (int s = 0; s < 4; ++s) bfrg[s] = *(const bf16x8*)(bp + s * 32);
#pragma unroll
    for (int s = 0; s < 4; ++s) {
#pragma unroll
      for (int g = 0; g < 2; ++g)
        acc[g][t] = __builtin_amdgcn_mfma_f32_16x16x32_bf16(afr[g][s], bfrg[s], acc[g][t],
                                                            0, 0, 0);
    }
  }

  // na partials: D layout col = cl, row = qg*4 + reg (+ g*16)
  float pa[2][4];
#pragma unroll
  for (int g = 0; g < 2; ++g)
#pragma unroll
    for (int reg = 0; reg < 4; ++reg) pa[g][reg] = 0.f;
#pragma unroll
  for (int g = 0; g < 2; ++g)
#pragma unroll
    for (int t = 0; t < 8; ++t)
#pragma unroll
      for (int reg = 0; reg < 4; ++reg)
        pa[g][reg] = fmaf(acc[g][t][reg] + bv[t], anv[t], pa[g][reg]);
#pragma unroll
  for (int g = 0; g < 2; ++g)
#pragma unroll
    for (int reg = 0; reg < 4; ++reg) {
      float v = pa[g][reg];
      v += __shfl_xor(v, 1, 64);
      v += __shfl_xor(v, 2, 64);
      v += __shfl_xor(v, 4, 64);
      v += __shfl_xor(v, 8, 64);
      pa[g][reg] = v;
    }
  if (cl == 0) {
#pragma unroll
    for (int g = 0; g < 2; ++g)
#pragma unroll
      for (int reg = 0; reg < 4; ++reg) {
        int r = rbase + g * 16 + qg * 4 + reg;
        if (r < nrows) na[r] = pa[g][reg];
      }
  }

  // epilogue: stage h tile (bf16) through LDS (reuse sWT), then coalesced store
  __syncthreads();
  u16* st = sWT + w * 32 * 136;
#pragma unroll
  for (int g = 0; g < 2; ++g)
#pragma unroll
    for (int t = 0; t < 8; ++t)
#pragma unroll
      for (int reg = 0; reg < 4; ++reg)
        st[(g * 16 + qg * 4 + reg) * 136 + t * 16 + cl] = f2bf(acc[g][t][reg] + bv[t]);
#pragma unroll
  for (int it = 0; it < 8; ++it) {
    int idx = it * 64 + lane;  // 32 rows x 16 chunks of 8 bf16
    int row = idx >> 4, c = idx & 15;
    u16x8 v = *(const u16x8*)(st + row * 136 + c * 8);
    int r = rbase + row;
    if (r < nrows) *(u16x8*)(h + (size_t)r * 128 + c * 8) = v;
  }
}

// ---------------- online softmax reductions ----------------
__device__ __forceinline__ void merge_write(float m, float s, float2* __restrict__ pairs) {
  for (int o = 1; o < 64; o <<= 1) {
    float om = __shfl_xor(m, o, 64), os = __shfl_xor(s, o, 64);
    float nm = fmaxf(m, om);
    s = s * __expf(m - nm) + os * __expf(om - nm);
    m = nm;
  }
  __shared__ float sm[4], ss[4];
  int t = threadIdx.x;
  if ((t & 63) == 0) { sm[t >> 6] = m; ss[t >> 6] = s; }
  __syncthreads();
  if (t == 0) {
    for (int k = 1; k < 4; ++k) {
      float nm = fmaxf(m, sm[k]);
      s = s * __expf(m - nm) + ss[k] * __expf(sm[k] - nm);
      m = nm;
    }
    pairs[blockIdx.x] = make_float2(m, s);
  }
}

// softmax1 factorized over nodes: max over deg>0 nodes; sum = sum deg*exp(na-m)
__global__ void k_sm1(const float* __restrict__ na, const int* __restrict__ deg, int n,
                      float2* __restrict__ pairs) {
  float m = -1e30f, s = 0.f;
  int i = blockIdx.x * blockDim.x + threadIdx.x;
  int st = gridDim.x * blockDim.x;
  for (; i < n; i += st) {
    int d = deg[i];
    if (d > 0) {
      float xv = na[i];
      if (xv > m) { s *= __expf(m - xv); m = xv; }
      s += (float)d * __expf(xv - m);
    }
  }
  merge_write(m, s, pairs);
}

// softmax2 single online pass over E
__global__ void k_sm2(const float* __restrict__ ea, const float* __restrict__ na,
                      const int* __restrict__ hs, const int* __restrict__ hd, int n,
                      float2* __restrict__ pairs) {
  float m = -1e30f, s = 0.f;
  int i = blockIdx.x * blockDim.x + threadIdx.x;
  int st = gridDim.x * blockDim.x;
  for (; i < n; i += st) {
    float xv = ea[hs[i]] + na[hd[i]];
    if (xv > m) { s *= __expf(m - xv); m = xv; }
    s += __expf(xv - m);
  }
  merge_write(m, s, pairs);
}

__global__ void k_smfin(const float2* __restrict__ pairs, int nb, float* __restrict__ out) {
  int t = threadIdx.x;
  float m = -1e30f, s = 0.f;
  for (int i = t; i < nb; i += 256) {
    float2 pr = pairs[i];
    float nm = fmaxf(m, pr.x);
    s = s * __expf(m - nm) + pr.y * __expf(pr.x - nm);
    m = nm;
  }
  for (int o = 1; o < 64; o <<= 1) {
    float om = __shfl_xor(m, o, 64), os = __shfl_xor(s, o, 64);
    float nm = fmaxf(m, om);
    s = s * __expf(m - nm) + os * __expf(om - nm);
    m = nm;
  }
  __shared__ float sm[4], ss[4];
  if ((t & 63) == 0) { sm[t >> 6] = m; ss[t >> 6] = s; }
  __syncthreads();
  if (t == 0) {
    for (int k = 1; k < 4; ++k) {
      float nm = fmaxf(m, sm[k]);
      s = s * __expf(m - nm) + ss[k] * __expf(sm[k] - nm);
      m = nm;
    }
    out[0] = m;
    out[1] = s;
  }
}

__global__ void k_wnode(const float* __restrict__ na, const float* __restrict__ sc,
                        float* __restrict__ w, int n) {
  float mx = sc[0];
  float iz = 1.0f / sc[1];
  int i = blockIdx.x * blockDim.x + threadIdx.x;
  if (i < n) w[i] = __expf(na[i] - mx) * iz;
}

__global__ void k_pe(const float* __restrict__ ea, const float* __restrict__ sc,
                     float* __restrict__ pe, int m) {
  float mx = sc[0];
  float iz = 1.0f / sc[1];
  int i = blockIdx.x * blockDim.x + threadIdx.x;
  if (i < m) pe[i] = __expf(ea[i] - mx) * iz;
}

// ---------------- segment sums (one wave/segment, 16B/lane, 4 edges/iter) ----------------
__global__ __launch_bounds__(256) void k_segA(
    const u16* __restrict__ h, const float* __restrict__ w,
    const int* __restrict__ csrc, const int* __restrict__ off,
    const float* __restrict__ ae, u16* __restrict__ he,
    float* __restrict__ ea, int m_count) {
  int wid = (blockIdx.x << 2) + (threadIdx.x >> 6);
  if (wid >= m_count) return;
  int lane = threadIdx.x & 63;
  int sub = lane >> 4, cl = lane & 15;
  int s = off[wid], t = off[wid + 1];
  float ax[8];
#pragma unroll
  for (int j = 0; j < 8; ++j) ax[j] = 0.f;
  for (int i = s + sub; i < t; i += 4) {
    int sr = csrc[i];
    float ww = w[sr];
    u16x8 v = *(const u16x8*)(h + (size_t)sr * 128 + cl * 8);
#pragma unroll
    for (int j = 0; j < 8; ++j) ax[j] = fmaf(ww, bf2f(v[j]), ax[j]);
  }
#pragma unroll
  for (int j = 0; j < 8; ++j) {
    ax[j] += __shfl_xor(ax[j], 16, 64);
    ax[j] += __shfl_xor(ax[j], 32, 64);
  }
  float4 a0 = *(const float4*)(ae + cl * 8);
  float4 a1 = *(const float4*)(ae + cl * 8 + 4);
  float pa = ax[0] * a0.x + ax[1] * a0.y + ax[2] * a0.z + ax[3] * a0.w +
             ax[4] * a1.x + ax[5] * a1.y + ax[6] * a1.z + ax[7] * a1.w;
  pa += __shfl_xor(pa, 1, 64);
  pa += __shfl_xor(pa, 2, 64);
  pa += __shfl_xor(pa, 4, 64);
  pa += __shfl_xor(pa, 8, 64);
  if (sub == 0) {
    u16x8 o;
#pragma unroll
    for (int j = 0; j < 8; ++j) o[j] = f2bf(ax[j]);
    *(u16x8*)(he + (size_t)wid * 128 + cl * 8) = o;
    if (cl == 0) ea[wid] = pa;
  }
}

__global__ __launch_bounds__(256) void k_segB(
    const u16* __restrict__ he, const float* __restrict__ pe,
    const float* __restrict__ na, const int* __restrict__ csrc,
    const int* __restrict__ off, float* __restrict__ y, int n_count, int relu) {
  int wid = (blockIdx.x << 2) + (threadIdx.x >> 6);
  if (wid >= n_count) return;
  int lane = threadIdx.x & 63;
  int sub = lane >> 4, cl = lane & 15;
  float rf = __expf(na[wid]);  // exp(ea+na-mx)/Z = pe[sr]*exp(na)
  int s = off[wid], t = off[wid + 1];
  float ax[8];
#pragma unroll
  for (int j = 0; j < 8; ++j) ax[j] = 0.f;
  for (int i = s + sub; i < t; i += 4) {
    int sr = csrc[i];
    float c = pe[sr];
    u16x8 v = *(const u16x8*)(he + (size_t)sr * 128 + cl * 8);
#pragma unroll
    for (int j = 0; j < 8; ++j) ax[j] = fmaf(c, bf2f(v[j]), ax[j]);
  }
#pragma unroll
  for (int j = 0; j < 8; ++j) {
    ax[j] += __shfl_xor(ax[j], 16, 64);
    ax[j] += __shfl_xor(ax[j], 32, 64);
    ax[j] *= rf;
    if (relu) ax[j] = fmaxf(ax[j], 0.f);
  }
  if (sub == 0) {
    float4 A = make_float4(ax[0], ax[1], ax[2], ax[3]);
    float4 B = make_float4(ax[4], ax[5], ax[6], ax[7]);
    *(float4*)(y + (size_t)wid * 128 + cl * 8) = A;
    *(float4*)(y + (size_t)wid * 128 + cl * 8 + 4) = B;
  }
}

// ---------------- host ----------------
extern "C" void kernel_launch(void* const* d_in, const int* in_sizes, int n_in,
                              void* d_out, int out_size, void* d_ws, size_t ws_size,
                              hipStream_t stream) {
  const int N = NCONST, M = MCONST, E = ECONST;
  const float* x = (const float*)d_in[0];
  const int* in_src = (const int*)d_in[1];
  const int* in_dst = (const int*)d_in[2];
  const int* has_src = (const int*)d_in[3];
  const int* has_dst = (const int*)d_in[4];
  const float* W1 = (const float*)d_in[5];
  const float* b1 = (const float*)d_in[6];
  const float* an1 = (const float*)d_in[7];
  const float* ae1 = (const float*)d_in[8];
  const float* W2 = (const float*)d_in[9];
  const float* b2 = (const float*)d_in[10];
  const float* an2 = (const float*)d_in[11];
  const float* ae2 = (const float*)d_in[12];

  char* p = (char*)d_ws;
  auto alloc = [&](size_t bytes) {
    char* q = p;
    p += (bytes + 255) & ~(size_t)255;
    return q;
  };
  u16* h = (u16*)alloc((size_t)N * 128 * 2);
  u16* he = (u16*)alloc((size_t)M * 128 * 2);
  float* na = (float*)alloc((size_t)N * 4);
  float* ea = (float*)alloc((size_t)M * 4);
  float* wn = (float*)alloc((size_t)N * 4);
  float* pe = (float*)alloc((size_t)M * 4);
  int* off_in = (int*)alloc((size_t)(M + 1) * 4);
  int* off_has = (int*)alloc((size_t)(N + 1) * 4);
  int* csrc_in = (int*)alloc((size_t)E * 4);
  int* csrc_has = (int*)alloc((size_t)E * 4);
  int* ebuf = (int*)alloc((size_t)E * 4);
  int* bsum = (int*)alloc(256 * 4);
  int* bcur = (int*)alloc(32768 * 4);
  float2* pairs = (float2*)alloc(256 * 8);
  float* scal = (float*)alloc(64);
  char* zbase = p;
  int* cnt_in = (int*)alloc((size_t)M * 4);
  int* cnt_has = (int*)alloc((size_t)N * 4);
  int* deg_src = (int*)alloc((size_t)N * 4);
  size_t zbytes = (size_t)(p - zbase);
  if ((size_t)(p - (char*)d_ws) > ws_size) return;  // insufficient workspace

  hipMemsetAsync(zbase, 0, zbytes, stream);

  // CSR build (shared by both layers)
  k_hist3<<<1024, 256, 0, stream>>>(in_dst, has_dst, in_src, E, cnt_in, cnt_has, deg_src);
  int nb_in = (M + 1023) / 1024;
  k_scan1<<<nb_in, 256, 0, stream>>>(cnt_in, M, off_in, bsum);
  k_scan2<<<1, 256, 0, stream>>>(bsum, nb_in);
  k_scan3<<<256, 256, 0, stream>>>(off_in, M, bsum);
  int nb_has = (N + 1023) / 1024;
  k_scan1<<<nb_has, 256, 0, stream>>>(cnt_has, N, off_has, bsum);
  k_scan2<<<1, 256, 0, stream>>>(bsum, nb_has);
  k_scan3<<<512, 256, 0, stream>>>(off_has, N, bsum);

  // bucketed scatter: in shift=1 (10000 buckets), has shift=2 (25000 buckets)
  const int SH_IN = 1, NB_IN = (MCONST + (1 << SH_IN) - 1) >> SH_IN;
  const int SH_HAS = 2, NB_HAS = (NCONST + (1 << SH_HAS) - 1) >> SH_HAS;
  k_binit<<<(NB_IN + 255) / 256, 256, 0, stream>>>(off_in, M, SH_IN, NB_IN, bcur);
  k_part<<<1024, 256, 0, stream>>>(in_dst, in_src, E, SH_IN, bcur, ebuf);
  k_final<SH_IN><<<NB_IN, 64, 0, stream>>>(off_in, M, ebuf, csrc_in);
  k_binit<<<(NB_HAS + 255) / 256, 256, 0, stream>>>(off_has, N, SH_HAS, NB_HAS, bcur);
  k_part<<<1024, 256, 0, stream>>>(has_dst, has_src, E, SH_HAS, bcur, ebuf);
  k_final<SH_HAS><<<NB_HAS, 64, 0, stream>>>(off_has, N, ebuf, csrc_has);

  auto layer = [&](const float* xin, const float* W, const float* b, const float* an_,
                   const float* ae_, float* yout, int relu) {
    k_fc<<<(N + 127) / 128, 256, 0, stream>>>(xin, W, b, an_, h, na, N);
    k_sm1<<<256, 256, 0, stream>>>(na, deg_src, N, pairs);
    k_smfin<<<1, 256, 0, stream>>>(pairs, 256, scal);
    k_wnode<<<(N + 255) / 256, 256, 0, stream>>>(na, scal, wn, N);
    k_segA<<<(M + 3) / 4, 256, 0, stream>>>(h, wn, csrc_in, off_in, ae_, he, ea, M);
    k_sm2<<<256, 256, 0, stream>>>(ea, na, has_src, has_dst, E, pairs);
    k_smfin<<<1, 256, 0, stream>>>(pairs, 256, scal + 2);
    k_pe<<<(M + 255) / 256, 256, 0, stream>>>(ea, scal + 2, pe, M);
    k_segB<<<(N + 3) / 4, 256, 0, stream>>>(he, pe, na, csrc_has, off_has, yout, N, relu);
  };

  layer(x, W1, b1, an1, ae1, (float*)d_out, 1);
  layer((const float*)d_out, W2, b2, an2, ae2, (float*)d_out, 0);
}

// Round 7
// 697.953 us; speedup vs baseline: 2.6583x; 1.1998x over previous
//
#include <hip/hip_runtime.h>
#include <hip/hip_bf16.h>
#include <math.h>

// HGAT: 2-layer hypergraph attention. N nodes, M hyperedges, E incidence edges, D=128.
// R7: histogram redone — R6's k_hist3 (4.8M device-scope atomics) wrote 149MB to HBM
// (~31B/atomic write-through) = 196us. Now two-phase LDS-privatized histogram with ZERO
// global atomics: k_hpart (32 blocks x chunk, 64KB LDS private counts, coalesced partial
// dump) + k_hred (sum 32 partials/counter). partial[] unions with ebuf. Memset dropped.
// Scatter (R5 bucketed, ballot-ranked), MFMA fc, bf16 rows unchanged.

typedef unsigned int u32;
typedef unsigned short u16;
typedef u16 u16x8 __attribute__((ext_vector_type(8)));
typedef short bf16x8 __attribute__((ext_vector_type(8)));
typedef float f32x4 __attribute__((ext_vector_type(4)));

#define NCONST 100000
#define MCONST 20000
#define ECONST 1600000
#define HCH 16384  // histogram chunk (ints) = 64KB LDS
#define HBC 32     // blocks per chunk

__device__ __forceinline__ u16 f2bf(float f) {  // RNE
  u32 u = __float_as_uint(f);
  u += 0x7FFFu + ((u >> 16) & 1u);
  return (u16)(u >> 16);
}
__device__ __forceinline__ float bf2f(u16 b) {
  return __uint_as_float(((u32)b) << 16);
}

// ---------------- two-phase LDS histogram (no global atomics) ----------------
__global__ __launch_bounds__(256) void k_hpart(const int* __restrict__ arr, int n,
                                               int* __restrict__ partial) {
  __shared__ int hc[HCH];
  int lo = blockIdx.y * HCH;
  for (int i = threadIdx.x; i < HCH; i += 256) hc[i] = 0;
  __syncthreads();
  int stride = gridDim.x * 256;
  int n4 = n >> 2;
  const int4* a4 = (const int4*)arr;
  for (int i = blockIdx.x * 256 + threadIdx.x; i < n4; i += stride) {
    int4 v = a4[i];
    u32 a = (u32)(v.x - lo), b = (u32)(v.y - lo), c = (u32)(v.z - lo), d = (u32)(v.w - lo);
    if (a < HCH) atomicAdd(&hc[a], 1);
    if (b < HCH) atomicAdd(&hc[b], 1);
    if (c < HCH) atomicAdd(&hc[c], 1);
    if (d < HCH) atomicAdd(&hc[d], 1);
  }
  for (int i = (n4 << 2) + blockIdx.x * 256 + threadIdx.x; i < n; i += stride) {
    u32 v = (u32)(arr[i] - lo);
    if (v < HCH) atomicAdd(&hc[v], 1);
  }
  __syncthreads();
  int* out = partial + ((size_t)blockIdx.y * gridDim.x + blockIdx.x) * HCH;
  for (int i = threadIdx.x; i < HCH; i += 256) out[i] = hc[i];
}

__global__ void k_hred(const int* __restrict__ partial, int range, int* __restrict__ cnt) {
  int j = blockIdx.x * 256 + threadIdx.x;
  if (j >= range) return;
  int chunk = j / HCH, jloc = j & (HCH - 1);
  const int* p = partial + (size_t)chunk * HBC * HCH + jloc;
  int s = 0;
#pragma unroll
  for (int b = 0; b < HBC; ++b) s += p[(size_t)b * HCH];
  cnt[j] = s;
}

// ---------------- scans ----------------
__global__ void k_scan1(const int* __restrict__ cnt, int n, int* __restrict__ off,
                        int* __restrict__ bsum) {
  __shared__ int sd[256];
  int t = threadIdx.x;
  int base = blockIdx.x * 1024 + t * 4;
  int v0 = (base + 0 < n) ? cnt[base + 0] : 0;
  int v1 = (base + 1 < n) ? cnt[base + 1] : 0;
  int v2 = (base + 2 < n) ? cnt[base + 2] : 0;
  int v3 = (base + 3 < n) ? cnt[base + 3] : 0;
  v1 += v0; v2 += v1; v3 += v2;
  int tot = v3;
  sd[t] = tot;
  __syncthreads();
  for (int o = 1; o < 256; o <<= 1) {
    int x = (t >= o) ? sd[t - o] : 0;
    __syncthreads();
    sd[t] += x;
    __syncthreads();
  }
  int excl = sd[t] - tot;
  if (base + 0 < n) off[base + 1] = v0 + excl;
  if (base + 1 < n) off[base + 2] = v1 + excl;
  if (base + 2 < n) off[base + 3] = v2 + excl;
  if (base + 3 < n) off[base + 4] = v3 + excl;
  if (t == 255) bsum[blockIdx.x] = sd[255];
}

__global__ void k_scan2(int* __restrict__ bsum, int nb) {
  __shared__ int sd[256];
  int t = threadIdx.x;
  int v = (t < nb) ? bsum[t] : 0;
  sd[t] = v;
  __syncthreads();
  for (int o = 1; o < 256; o <<= 1) {
    int x = (t >= o) ? sd[t - o] : 0;
    __syncthreads();
    sd[t] += x;
    __syncthreads();
  }
  if (t < nb) bsum[t] = sd[t] - v;  // exclusive
}

__global__ void k_scan3(int* __restrict__ off, int n, const int* __restrict__ bsum) {
  int i = blockIdx.x * blockDim.x + threadIdx.x;
  int st = gridDim.x * blockDim.x;
  if (blockIdx.x == 0 && threadIdx.x == 0) off[0] = 0;
  for (; i < n; i += st) off[i + 1] += bsum[i >> 10];
}

// bucketed scatter pass 1: claim slot in bucket region, write packed (dloc<<20)|src
__global__ void k_binit(const int* __restrict__ off, int segs, int shift, int nb,
                        int* __restrict__ bcur) {
  int b = blockIdx.x * blockDim.x + threadIdx.x;
  if (b < nb) bcur[b] = off[min(b << shift, segs)];
}

__global__ void k_part(const int* __restrict__ dst, const int* __restrict__ srcv, int n,
                       int shift, int* __restrict__ bcur, int* __restrict__ ebuf) {
  int i = blockIdx.x * blockDim.x + threadIdx.x;
  int st = gridDim.x * blockDim.x;
  int msk = (1 << shift) - 1;
  for (; i < n; i += st) {
    int d = dst[i], s = srcv[i];
    int pos = atomicAdd(&bcur[d >> shift], 1);
    ebuf[pos] = ((d & msk) << 20) | s;
  }
}

// pass 2: one wave per bucket; within-bucket slotting by ballot rank (no atomics)
template <int SHIFT>
__global__ __launch_bounds__(64) void k_final(const int* __restrict__ off, int segs,
                                              const int* __restrict__ ebuf,
                                              int* __restrict__ csrc) {
  const int NSEG = 1 << SHIFT;
  int b = blockIdx.x;
  int seg0 = b << SHIFT;
  if (seg0 >= segs) return;
  int segN = min(seg0 + NSEG, segs);
  int start = off[seg0], end = off[segN];
  int lane = threadIdx.x;
  unsigned long long below = (1ull << lane) - 1;
  int cnt[NSEG];
#pragma unroll
  for (int s = 0; s < NSEG; ++s) cnt[s] = 0;
  for (int base = start; base < end; base += 64) {
    int i = base + lane;
    int v = (i < end) ? ebuf[i] : -1;
    int dloc = v >> 20;  // -1 for inactive lanes, never matches s
    int src = v & 0xFFFFF;
#pragma unroll
    for (int s = 0; s < NSEG; ++s) {
      unsigned long long mask = __ballot(dloc == s);
      if (dloc == s) {
        int rank = __popcll(mask & below);
        csrc[off[seg0 + s] + cnt[s] + rank] = src;
      }
      cnt[s] += __popcll(mask);
    }
  }
}

// ---------------- FC: h = x@W + b (bf16 out), na = h@an  [MFMA 16x16x32 bf16] ------------
// block = 256 thr = 4 waves; wave owns 32 rows x 128 cols; K=128.
// LDS: WT[j][k] bf16, row stride 136 (2-way bank alias = free); reused as epilogue staging.
__global__ __launch_bounds__(256, 2) void k_fc(
    const float* __restrict__ x, const float* __restrict__ W,
    const float* __restrict__ bias, const float* __restrict__ an,
    u16* __restrict__ h, float* __restrict__ na, int nrows) {
  __shared__ __align__(16) u16 sWT[128 * 136];
  int tid = threadIdx.x;
  int lane = tid & 63, w = tid >> 6;
  int cl = lane & 15, qg = lane >> 4;

  // stage WT = W^T bf16 (W is [k][j] row-major fp32)
  for (int i = tid * 4; i < 16384; i += 1024) {
    float4 v = *(const float4*)(W + i);
    int k = i >> 7, j = i & 127;
    sWT[(j + 0) * 136 + k] = f2bf(v.x);
    sWT[(j + 1) * 136 + k] = f2bf(v.y);
    sWT[(j + 2) * 136 + k] = f2bf(v.z);
    sWT[(j + 3) * 136 + k] = f2bf(v.w);
  }

  float anv[8], bv[8];
#pragma unroll
  for (int t = 0; t < 8; ++t) {
    anv[t] = an[t * 16 + cl];
    bv[t] = bias[t * 16 + cl];
  }

  // A fragments: rows rbase..rbase+31, fp32 -> bf16 in-register
  int rbase = blockIdx.x * 128 + w * 32;
  bf16x8 afr[2][4];
#pragma unroll
  for (int g = 0; g < 2; ++g) {
    int r = rbase + g * 16 + cl;
    int rc = min(r, nrows - 1);
    const float* xp = x + (size_t)rc * 128 + qg * 8;
#pragma unroll
    for (int s = 0; s < 4; ++s) {
      float4 u0 = *(const float4*)(xp + s * 32);
      float4 u1 = *(const float4*)(xp + s * 32 + 4);
      bf16x8 a;
      a[0] = (short)f2bf(u0.x); a[1] = (short)f2bf(u0.y);
      a[2] = (short)f2bf(u0.z); a[3] = (short)f2bf(u0.w);
      a[4] = (short)f2bf(u1.x); a[5] = (short)f2bf(u1.y);
      a[6] = (short)f2bf(u1.z); a[7] = (short)f2bf(u1.w);
      afr[g][s] = a;
    }
  }
  __syncthreads();

  f32x4 acc[2][8];
#pragma unroll
  for (int g = 0; g < 2; ++g)
#pragma unroll
    for (int t = 0; t < 8; ++t) {
      acc[g][t][0] = 0.f; acc[g][t][1] = 0.f; acc[g][t][2] = 0.f; acc[g][t][3] = 0.f;
    }

#pragma unroll
  for (int t = 0; t < 8; ++t) {
    bf16x8 bfrg[4];
    const u16* bp = sWT + (t * 16 + cl) * 136 + qg * 8;
#pragma unroll
    for (int s = 0; s < 4; ++s) bfrg[s] = *(const bf16x8*)(bp + s * 32);
#pragma unroll
    for (int s = 0; s < 4; ++s) {
#pragma unroll
      for (int g = 0; g < 2; ++g)
        acc[g][t] = __builtin_amdgcn_mfma_f32_16x16x32_bf16(afr[g][s], bfrg[s], acc[g][t],
                                                            0, 0, 0);
    }
  }

  // na partials: D layout col = cl, row = qg*4 + reg (+ g*16)
  float pa[2][4];
#pragma unroll
  for (int g = 0; g < 2; ++g)
#pragma unroll
    for (int reg = 0; reg < 4; ++reg) pa[g][reg] = 0.f;
#pragma unroll
  for (int g = 0; g < 2; ++g)
#pragma unroll
    for (int t = 0; t < 8; ++t)
#pragma unroll
      for (int reg = 0; reg < 4; ++reg)
        pa[g][reg] = fmaf(acc[g][t][reg] + bv[t], anv[t], pa[g][reg]);
#pragma unroll
  for (int g = 0; g < 2; ++g)
#pragma unroll
    for (int reg = 0; reg < 4; ++reg) {
      float v = pa[g][reg];
      v += __shfl_xor(v, 1, 64);
      v += __shfl_xor(v, 2, 64);
      v += __shfl_xor(v, 4, 64);
      v += __shfl_xor(v, 8, 64);
      pa[g][reg] = v;
    }
  if (cl == 0) {
#pragma unroll
    for (int g = 0; g < 2; ++g)
#pragma unroll
      for (int reg = 0; reg < 4; ++reg) {
        int r = rbase + g * 16 + qg * 4 + reg;
        if (r < nrows) na[r] = pa[g][reg];
      }
  }

  // epilogue: stage h tile (bf16) through LDS (reuse sWT), then coalesced store
  __syncthreads();
  u16* st = sWT + w * 32 * 136;
#pragma unroll
  for (int g = 0; g < 2; ++g)
#pragma unroll
    for (int t = 0; t < 8; ++t)
#pragma unroll
      for (int reg = 0; reg < 4; ++reg)
        st[(g * 16 + qg * 4 + reg) * 136 + t * 16 + cl] = f2bf(acc[g][t][reg] + bv[t]);
#pragma unroll
  for (int it = 0; it < 8; ++it) {
    int idx = it * 64 + lane;  // 32 rows x 16 chunks of 8 bf16
    int row = idx >> 4, c = idx & 15;
    u16x8 v = *(const u16x8*)(st + row * 136 + c * 8);
    int r = rbase + row;
    if (r < nrows) *(u16x8*)(h + (size_t)r * 128 + c * 8) = v;
  }
}

// ---------------- online softmax reductions ----------------
__device__ __forceinline__ void merge_write(float m, float s, float2* __restrict__ pairs) {
  for (int o = 1; o < 64; o <<= 1) {
    float om = __shfl_xor(m, o, 64), os = __shfl_xor(s, o, 64);
    float nm = fmaxf(m, om);
    s = s * __expf(m - nm) + os * __expf(om - nm);
    m = nm;
  }
  __shared__ float sm[4], ss[4];
  int t = threadIdx.x;
  if ((t & 63) == 0) { sm[t >> 6] = m; ss[t >> 6] = s; }
  __syncthreads();
  if (t == 0) {
    for (int k = 1; k < 4; ++k) {
      float nm = fmaxf(m, sm[k]);
      s = s * __expf(m - nm) + ss[k] * __expf(sm[k] - nm);
      m = nm;
    }
    pairs[blockIdx.x] = make_float2(m, s);
  }
}

// softmax1 factorized over nodes: max over deg>0 nodes; sum = sum deg*exp(na-m)
__global__ void k_sm1(const float* __restrict__ na, const int* __restrict__ deg, int n,
                      float2* __restrict__ pairs) {
  float m = -1e30f, s = 0.f;
  int i = blockIdx.x * blockDim.x + threadIdx.x;
  int st = gridDim.x * blockDim.x;
  for (; i < n; i += st) {
    int d = deg[i];
    if (d > 0) {
      float xv = na[i];
      if (xv > m) { s *= __expf(m - xv); m = xv; }
      s += (float)d * __expf(xv - m);
    }
  }
  merge_write(m, s, pairs);
}

// softmax2 single online pass over E
__global__ void k_sm2(const float* __restrict__ ea, const float* __restrict__ na,
                      const int* __restrict__ hs, const int* __restrict__ hd, int n,
                      float2* __restrict__ pairs) {
  float m = -1e30f, s = 0.f;
  int i = blockIdx.x * blockDim.x + threadIdx.x;
  int st = gridDim.x * blockDim.x;
  for (; i < n; i += st) {
    float xv = ea[hs[i]] + na[hd[i]];
    if (xv > m) { s *= __expf(m - xv); m = xv; }
    s += __expf(xv - m);
  }
  merge_write(m, s, pairs);
}

__global__ void k_smfin(const float2* __restrict__ pairs, int nb, float* __restrict__ out) {
  int t = threadIdx.x;
  float m = -1e30f, s = 0.f;
  for (int i = t; i < nb; i += 256) {
    float2 pr = pairs[i];
    float nm = fmaxf(m, pr.x);
    s = s * __expf(m - nm) + pr.y * __expf(pr.x - nm);
    m = nm;
  }
  for (int o = 1; o < 64; o <<= 1) {
    float om = __shfl_xor(m, o, 64), os = __shfl_xor(s, o, 64);
    float nm = fmaxf(m, om);
    s = s * __expf(m - nm) + os * __expf(om - nm);
    m = nm;
  }
  __shared__ float sm[4], ss[4];
  if ((t & 63) == 0) { sm[t >> 6] = m; ss[t >> 6] = s; }
  __syncthreads();
  if (t == 0) {
    for (int k = 1; k < 4; ++k) {
      float nm = fmaxf(m, sm[k]);
      s = s * __expf(m - nm) + ss[k] * __expf(sm[k] - nm);
      m = nm;
    }
    out[0] = m;
    out[1] = s;
  }
}

__global__ void k_wnode(const float* __restrict__ na, const float* __restrict__ sc,
                        float* __restrict__ w, int n) {
  float mx = sc[0];
  float iz = 1.0f / sc[1];
  int i = blockIdx.x * blockDim.x + threadIdx.x;
  if (i < n) w[i] = __expf(na[i] - mx) * iz;
}

__global__ void k_pe(const float* __restrict__ ea, const float* __restrict__ sc,
                     float* __restrict__ pe, int m) {
  float mx = sc[0];
  float iz = 1.0f / sc[1];
  int i = blockIdx.x * blockDim.x + threadIdx.x;
  if (i < m) pe[i] = __expf(ea[i] - mx) * iz;
}

// ---------------- segment sums (one wave/segment, 16B/lane, 4 edges/iter) ----------------
__global__ __launch_bounds__(256) void k_segA(
    const u16* __restrict__ h, const float* __restrict__ w,
    const int* __restrict__ csrc, const int* __restrict__ off,
    const float* __restrict__ ae, u16* __restrict__ he,
    float* __restrict__ ea, int m_count) {
  int wid = (blockIdx.x << 2) + (threadIdx.x >> 6);
  if (wid >= m_count) return;
  int lane = threadIdx.x & 63;
  int sub = lane >> 4, cl = lane & 15;
  int s = off[wid], t = off[wid + 1];
  float ax[8];
#pragma unroll
  for (int j = 0; j < 8; ++j) ax[j] = 0.f;
  for (int i = s + sub; i < t; i += 4) {
    int sr = csrc[i];
    float ww = w[sr];
    u16x8 v = *(const u16x8*)(h + (size_t)sr * 128 + cl * 8);
#pragma unroll
    for (int j = 0; j < 8; ++j) ax[j] = fmaf(ww, bf2f(v[j]), ax[j]);
  }
#pragma unroll
  for (int j = 0; j < 8; ++j) {
    ax[j] += __shfl_xor(ax[j], 16, 64);
    ax[j] += __shfl_xor(ax[j], 32, 64);
  }
  float4 a0 = *(const float4*)(ae + cl * 8);
  float4 a1 = *(const float4*)(ae + cl * 8 + 4);
  float pa = ax[0] * a0.x + ax[1] * a0.y + ax[2] * a0.z + ax[3] * a0.w +
             ax[4] * a1.x + ax[5] * a1.y + ax[6] * a1.z + ax[7] * a1.w;
  pa += __shfl_xor(pa, 1, 64);
  pa += __shfl_xor(pa, 2, 64);
  pa += __shfl_xor(pa, 4, 64);
  pa += __shfl_xor(pa, 8, 64);
  if (sub == 0) {
    u16x8 o;
#pragma unroll
    for (int j = 0; j < 8; ++j) o[j] = f2bf(ax[j]);
    *(u16x8*)(he + (size_t)wid * 128 + cl * 8) = o;
    if (cl == 0) ea[wid] = pa;
  }
}

__global__ __launch_bounds__(256) void k_segB(
    const u16* __restrict__ he, const float* __restrict__ pe,
    const float* __restrict__ na, const int* __restrict__ csrc,
    const int* __restrict__ off, float* __restrict__ y, int n_count, int relu) {
  int wid = (blockIdx.x << 2) + (threadIdx.x >> 6);
  if (wid >= n_count) return;
  int lane = threadIdx.x & 63;
  int sub = lane >> 4, cl = lane & 15;
  float rf = __expf(na[wid]);  // exp(ea+na-mx)/Z = pe[sr]*exp(na)
  int s = off[wid], t = off[wid + 1];
  float ax[8];
#pragma unroll
  for (int j = 0; j < 8; ++j) ax[j] = 0.f;
  for (int i = s + sub; i < t; i += 4) {
    int sr = csrc[i];
    float c = pe[sr];
    u16x8 v = *(const u16x8*)(he + (size_t)sr * 128 + cl * 8);
#pragma unroll
    for (int j = 0; j < 8; ++j) ax[j] = fmaf(c, bf2f(v[j]), ax[j]);
  }
#pragma unroll
  for (int j = 0; j < 8; ++j) {
    ax[j] += __shfl_xor(ax[j], 16, 64);
    ax[j] += __shfl_xor(ax[j], 32, 64);
    ax[j] *= rf;
    if (relu) ax[j] = fmaxf(ax[j], 0.f);
  }
  if (sub == 0) {
    float4 A = make_float4(ax[0], ax[1], ax[2], ax[3]);
    float4 B = make_float4(ax[4], ax[5], ax[6], ax[7]);
    *(float4*)(y + (size_t)wid * 128 + cl * 8) = A;
    *(float4*)(y + (size_t)wid * 128 + cl * 8 + 4) = B;
  }
}

// ---------------- host ----------------
extern "C" void kernel_launch(void* const* d_in, const int* in_sizes, int n_in,
                              void* d_out, int out_size, void* d_ws, size_t ws_size,
                              hipStream_t stream) {
  const int N = NCONST, M = MCONST, E = ECONST;
  const float* x = (const float*)d_in[0];
  const int* in_src = (const int*)d_in[1];
  const int* in_dst = (const int*)d_in[2];
  const int* has_src = (const int*)d_in[3];
  const int* has_dst = (const int*)d_in[4];
  const float* W1 = (const float*)d_in[5];
  const float* b1 = (const float*)d_in[6];
  const float* an1 = (const float*)d_in[7];
  const float* ae1 = (const float*)d_in[8];
  const float* W2 = (const float*)d_in[9];
  const float* b2 = (const float*)d_in[10];
  const float* an2 = (const float*)d_in[11];
  const float* ae2 = (const float*)d_in[12];

  const int NCH_M = (MCONST + HCH - 1) / HCH;  // 2
  const int NCH_N = (NCONST + HCH - 1) / HCH;  // 7
  const size_t PARTIAL_BYTES = (size_t)NCH_N * HBC * HCH * 4;  // 14.7 MB

  char* p = (char*)d_ws;
  auto alloc = [&](size_t bytes) {
    char* q = p;
    p += (bytes + 255) & ~(size_t)255;
    return q;
  };
  u16* h = (u16*)alloc((size_t)N * 128 * 2);
  u16* he = (u16*)alloc((size_t)M * 128 * 2);
  float* na = (float*)alloc((size_t)N * 4);
  float* ea = (float*)alloc((size_t)M * 4);
  float* wn = (float*)alloc((size_t)N * 4);
  float* pe = (float*)alloc((size_t)M * 4);
  int* off_in = (int*)alloc((size_t)(M + 1) * 4);
  int* off_has = (int*)alloc((size_t)(N + 1) * 4);
  int* csrc_in = (int*)alloc((size_t)E * 4);
  int* csrc_has = (int*)alloc((size_t)E * 4);
  int* partial = (int*)alloc(PARTIAL_BYTES);  // unions with ebuf (disjoint lifetime)
  int* ebuf = partial;
  int* bsum = (int*)alloc(256 * 4);
  int* bcur = (int*)alloc(32768 * 4);
  float2* pairs = (float2*)alloc(256 * 8);
  float* scal = (float*)alloc(64);
  int* cnt_in = (int*)alloc((size_t)M * 4);
  int* cnt_has = (int*)alloc((size_t)N * 4);
  int* deg_src = (int*)alloc((size_t)N * 4);
  if ((size_t)(p - (char*)d_ws) > ws_size) return;  // insufficient workspace

  // CSR build (shared by both layers) — atomic-free histograms
  k_hpart<<<dim3(HBC, NCH_M), 256, 0, stream>>>(in_dst, E, partial);
  k_hred<<<(M + 255) / 256, 256, 0, stream>>>(partial, M, cnt_in);
  k_hpart<<<dim3(HBC, NCH_N), 256, 0, stream>>>(has_dst, E, partial);
  k_hred<<<(N + 255) / 256, 256, 0, stream>>>(partial, N, cnt_has);
  k_hpart<<<dim3(HBC, NCH_N), 256, 0, stream>>>(in_src, E, partial);
  k_hred<<<(N + 255) / 256, 256, 0, stream>>>(partial, N, deg_src);

  int nb_in = (M + 1023) / 1024;
  k_scan1<<<nb_in, 256, 0, stream>>>(cnt_in, M, off_in, bsum);
  k_scan2<<<1, 256, 0, stream>>>(bsum, nb_in);
  k_scan3<<<256, 256, 0, stream>>>(off_in, M, bsum);
  int nb_has = (N + 1023) / 1024;
  k_scan1<<<nb_has, 256, 0, stream>>>(cnt_has, N, off_has, bsum);
  k_scan2<<<1, 256, 0, stream>>>(bsum, nb_has);
  k_scan3<<<512, 256, 0, stream>>>(off_has, N, bsum);

  // bucketed scatter: in shift=1 (10000 buckets), has shift=2 (25000 buckets)
  const int SH_IN = 1, NB_IN = (MCONST + (1 << SH_IN) - 1) >> SH_IN;
  const int SH_HAS = 2, NB_HAS = (NCONST + (1 << SH_HAS) - 1) >> SH_HAS;
  k_binit<<<(NB_IN + 255) / 256, 256, 0, stream>>>(off_in, M, SH_IN, NB_IN, bcur);
  k_part<<<1024, 256, 0, stream>>>(in_dst, in_src, E, SH_IN, bcur, ebuf);
  k_final<SH_IN><<<NB_IN, 64, 0, stream>>>(off_in, M, ebuf, csrc_in);
  k_binit<<<(NB_HAS + 255) / 256, 256, 0, stream>>>(off_has, N, SH_HAS, NB_HAS, bcur);
  k_part<<<1024, 256, 0, stream>>>(has_dst, has_src, E, SH_HAS, bcur, ebuf);
  k_final<SH_HAS><<<NB_HAS, 64, 0, stream>>>(off_has, N, ebuf, csrc_has);

  auto layer = [&](const float* xin, const float* W, const float* b, const float* an_,
                   const float* ae_, float* yout, int relu) {
    k_fc<<<(N + 127) / 128, 256, 0, stream>>>(xin, W, b, an_, h, na, N);
    k_sm1<<<256, 256, 0, stream>>>(na, deg_src, N, pairs);
    k_smfin<<<1, 256, 0, stream>>>(pairs, 256, scal);
    k_wnode<<<(N + 255) / 256, 256, 0, stream>>>(na, scal, wn, N);
    k_segA<<<(M + 3) / 4, 256, 0, stream>>>(h, wn, csrc_in, off_in, ae_, he, ea, M);
    k_sm2<<<256, 256, 0, stream>>>(ea, na, has_src, has_dst, E, pairs);
    k_smfin<<<1, 256, 0, stream>>>(pairs, 256, scal + 2);
    k_pe<<<(M + 255) / 256, 256, 0, stream>>>(ea, scal + 2, pe, M);
    k_segB<<<(N + 3) / 4, 256, 0, stream>>>(he, pe, na, csrc_has, off_has, yout, N, relu);
  };

  layer(x, W1, b1, an1, ae1, (float*)d_out, 1);
  layer((const float*)d_out, W2, b2, an2, ae2, (float*)d_out, 0);
}

// Round 8
// 532.890 us; speedup vs baseline: 3.4817x; 1.3098x over previous
//
#include <hip/hip_runtime.h>
#include <hip/hip_bf16.h>
#include <math.h>

// HGAT: 2-layer hypergraph attention. N nodes, M hyperedges, E incidence edges, D=128.
// R8: scatter v3 — atomic-free LDS-staged partition. R7's k_part (per-edge global claim
// + random 4B ebuf write) had 16x write amp (99MB for 6.4MB logical) = 133us each.
// Now: k_coarse (per-block LDS hist over coarse buckets -> bb[block][bucket]) ->
// k_colscan (per-bucket scan over blocks -> deterministic absolute bases, no atomics) ->
// k_stage (LDS-rank + stage 25KB + flush contiguous runs, ~1.5x amp) ->
// k_place (per-bucket LDS cursors, scatter csrc within hot 20KB window).
// Segment order within CSR is arbitrary (segment-sum is order-free to rounding).
// Fine histograms (R7), MFMA fc (R4), bf16 rows (R3) unchanged.

typedef unsigned int u32;
typedef unsigned short u16;
typedef u16 u16x8 __attribute__((ext_vector_type(8)));
typedef short bf16x8 __attribute__((ext_vector_type(8)));
typedef float f32x4 __attribute__((ext_vector_type(4)));

#define NCONST 100000
#define MCONST 20000
#define ECONST 1600000
#define HCH 16384  // fine-histogram chunk (ints) = 64KB LDS
#define HBC 32     // blocks per chunk

#define PBLK 256        // partition blocks (1 chunk each)
#define PT 6250         // edges per partition chunk (E/PBLK)
#define SHB_IN 6        // coarse bucket shift, in-direction (bucket = 64 segs)
#define NBK_IN 313      // ceil(M / 64)
#define SRCB_IN 17      // src bits (in_src < 100000 < 2^17)
#define SHB_HAS 8       // coarse bucket shift, has-direction (bucket = 256 segs)
#define NBK_HAS 391     // ceil(N / 256)
#define SRCB_HAS 15     // src bits (has_src < 20000 < 2^15)

__device__ __forceinline__ u16 f2bf(float f) {  // RNE
  u32 u = __float_as_uint(f);
  u += 0x7FFFu + ((u >> 16) & 1u);
  return (u16)(u >> 16);
}
__device__ __forceinline__ float bf2f(u16 b) {
  return __uint_as_float(((u32)b) << 16);
}

// ---------------- fine histograms (two-phase, no global atomics) ----------------
__global__ __launch_bounds__(256) void k_hpart(const int* __restrict__ arr, int n,
                                               int* __restrict__ partial) {
  __shared__ int hc[HCH];
  int lo = blockIdx.y * HCH;
  for (int i = threadIdx.x; i < HCH; i += 256) hc[i] = 0;
  __syncthreads();
  int stride = gridDim.x * 256;
  int n4 = n >> 2;
  const int4* a4 = (const int4*)arr;
  for (int i = blockIdx.x * 256 + threadIdx.x; i < n4; i += stride) {
    int4 v = a4[i];
    u32 a = (u32)(v.x - lo), b = (u32)(v.y - lo), c = (u32)(v.z - lo), d = (u32)(v.w - lo);
    if (a < HCH) atomicAdd(&hc[a], 1);
    if (b < HCH) atomicAdd(&hc[b], 1);
    if (c < HCH) atomicAdd(&hc[c], 1);
    if (d < HCH) atomicAdd(&hc[d], 1);
  }
  for (int i = (n4 << 2) + blockIdx.x * 256 + threadIdx.x; i < n; i += stride) {
    u32 v = (u32)(arr[i] - lo);
    if (v < HCH) atomicAdd(&hc[v], 1);
  }
  __syncthreads();
  int* out = partial + ((size_t)blockIdx.y * gridDim.x + blockIdx.x) * HCH;
  for (int i = threadIdx.x; i < HCH; i += 256) out[i] = hc[i];
}

__global__ void k_hred(const int* __restrict__ partial, int range, int* __restrict__ cnt) {
  int j = blockIdx.x * 256 + threadIdx.x;
  if (j >= range) return;
  int chunk = j / HCH, jloc = j & (HCH - 1);
  const int* p = partial + (size_t)chunk * HBC * HCH + jloc;
  int s = 0;
#pragma unroll
  for (int b = 0; b < HBC; ++b) s += p[(size_t)b * HCH];
  cnt[j] = s;
}

// ---------------- scans ----------------
__global__ void k_scan1(const int* __restrict__ cnt, int n, int* __restrict__ off,
                        int* __restrict__ bsum) {
  __shared__ int sd[256];
  int t = threadIdx.x;
  int base = blockIdx.x * 1024 + t * 4;
  int v0 = (base + 0 < n) ? cnt[base + 0] : 0;
  int v1 = (base + 1 < n) ? cnt[base + 1] : 0;
  int v2 = (base + 2 < n) ? cnt[base + 2] : 0;
  int v3 = (base + 3 < n) ? cnt[base + 3] : 0;
  v1 += v0; v2 += v1; v3 += v2;
  int tot = v3;
  sd[t] = tot;
  __syncthreads();
  for (int o = 1; o < 256; o <<= 1) {
    int x = (t >= o) ? sd[t - o] : 0;
    __syncthreads();
    sd[t] += x;
    __syncthreads();
  }
  int excl = sd[t] - tot;
  if (base + 0 < n) off[base + 1] = v0 + excl;
  if (base + 1 < n) off[base + 2] = v1 + excl;
  if (base + 2 < n) off[base + 3] = v2 + excl;
  if (base + 3 < n) off[base + 4] = v3 + excl;
  if (t == 255) bsum[blockIdx.x] = sd[255];
}

__global__ void k_scan2(int* __restrict__ bsum, int nb) {
  __shared__ int sd[256];
  int t = threadIdx.x;
  int v = (t < nb) ? bsum[t] : 0;
  sd[t] = v;
  __syncthreads();
  for (int o = 1; o < 256; o <<= 1) {
    int x = (t >= o) ? sd[t - o] : 0;
    __syncthreads();
    sd[t] += x;
    __syncthreads();
  }
  if (t < nb) bsum[t] = sd[t] - v;  // exclusive
}

__global__ void k_scan3(int* __restrict__ off, int n, const int* __restrict__ bsum) {
  int i = blockIdx.x * blockDim.x + threadIdx.x;
  int st = gridDim.x * blockDim.x;
  if (blockIdx.x == 0 && threadIdx.x == 0) off[0] = 0;
  for (; i < n; i += st) off[i + 1] += bsum[i >> 10];
}

// ---------------- scatter v3: atomic-free LDS-staged partition ----------------
// A: per-block coarse histograms for BOTH directions (one pass over both dst arrays)
__global__ __launch_bounds__(256) void k_coarse(const int* __restrict__ in_dst,
                                                const int* __restrict__ has_dst,
                                                int* __restrict__ bb_in,
                                                int* __restrict__ bb_has) {
  __shared__ int h1[NBK_IN];
  __shared__ int h2[NBK_HAS];
  for (int i = threadIdx.x; i < NBK_IN; i += 256) h1[i] = 0;
  for (int i = threadIdx.x; i < NBK_HAS; i += 256) h2[i] = 0;
  __syncthreads();
  int c0 = blockIdx.x * PT, c1 = min(c0 + PT, ECONST);
  for (int i = c0 + threadIdx.x; i < c1; i += 256) {
    atomicAdd(&h1[in_dst[i] >> SHB_IN], 1);
    atomicAdd(&h2[has_dst[i] >> SHB_HAS], 1);
  }
  __syncthreads();
  int* o1 = bb_in + (size_t)blockIdx.x * NBK_IN;
  for (int i = threadIdx.x; i < NBK_IN; i += 256) o1[i] = h1[i];
  int* o2 = bb_has + (size_t)blockIdx.x * NBK_HAS;
  for (int i = threadIdx.x; i < NBK_HAS; i += 256) o2[i] = h2[i];
}

// B: per-bucket exclusive scan over the 256 block counts -> absolute global bases
__global__ __launch_bounds__(256) void k_colscan(int* __restrict__ bb, int nbuk,
                                                 const int* __restrict__ off, int shb,
                                                 int segs) {
  __shared__ int sd[256];
  int b = blockIdx.x;
  int t = threadIdx.x;
  int v = bb[(size_t)t * nbuk + b];
  sd[t] = v;
  __syncthreads();
  for (int o = 1; o < 256; o <<= 1) {
    int x = (t >= o) ? sd[t - o] : 0;
    __syncthreads();
    sd[t] += x;
    __syncthreads();
  }
  bb[(size_t)t * nbuk + b] = sd[t] - v + off[min(b << shb, segs)];
}

// C: re-read chunk, LDS-rank by bucket, stage, flush contiguous runs to ebuf.
// packed: (bucket<<23) | (dloc<<SRCB) | src  — fits 32 bits for both directions.
template <int NBUK, int SHB, int SRCB>
__global__ __launch_bounds__(256) void k_stage(const int* __restrict__ dst,
                                               const int* __restrict__ srcv,
                                               const int* __restrict__ bb,
                                               int* __restrict__ ebuf) {
  __shared__ int hist[NBUK];   // later reused as rank cursor
  __shared__ int loff[NBUK];
  __shared__ int gbase[NBUK];
  __shared__ int stage[PT];
  __shared__ int sd[256];
  int t = threadIdx.x;
  for (int i = t; i < NBUK; i += 256) hist[i] = 0;
  __syncthreads();
  int c0 = blockIdx.x * PT, c1 = min(c0 + PT, ECONST);
  for (int i = c0 + t; i < c1; i += 256) atomicAdd(&hist[dst[i] >> SHB], 1);
  __syncthreads();
  // exclusive scan of hist (NBUK <= 512): 2 values per thread
  {
    int v0 = (2 * t < NBUK) ? hist[2 * t] : 0;
    int v1 = (2 * t + 1 < NBUK) ? hist[2 * t + 1] : 0;
    sd[t] = v0 + v1;
    __syncthreads();
    for (int o = 1; o < 256; o <<= 1) {
      int x = (t >= o) ? sd[t - o] : 0;
      __syncthreads();
      sd[t] += x;
      __syncthreads();
    }
    int excl = sd[t] - (v0 + v1);
    if (2 * t < NBUK) loff[2 * t] = excl;
    if (2 * t + 1 < NBUK) loff[2 * t + 1] = excl + v0;
  }
  __syncthreads();
  for (int i = t; i < NBUK; i += 256) {
    gbase[i] = bb[(size_t)blockIdx.x * NBUK + i];
    hist[i] = loff[i];  // cursor
  }
  __syncthreads();
  for (int i = c0 + t; i < c1; i += 256) {
    int d = dst[i], s = srcv[i];
    int b = d >> SHB;
    int r = atomicAdd(&hist[b], 1);
    stage[r] = (b << 23) | ((d & ((1 << SHB) - 1)) << SRCB) | s;
  }
  __syncthreads();
  int tot = c1 - c0;
  for (int i = t; i < tot; i += 256) {
    int v = stage[i];
    int b = ((u32)v) >> 23;
    ebuf[gbase[b] + (i - loff[b])] = v & ((1 << 23) - 1);
  }
}

// D: per-bucket placement: LDS cursors from off[], scatter csrc within hot window.
template <int SHB, int SRCB>
__global__ __launch_bounds__(256) void k_place(const int* __restrict__ off, int segs,
                                               const int* __restrict__ ebuf,
                                               int* __restrict__ csrc) {
  const int NSEG = 1 << SHB;
  __shared__ int cur[NSEG];
  int seg0 = blockIdx.x << SHB;
  if (seg0 >= segs) return;
  int segN = min(seg0 + NSEG, segs);
  for (int i = threadIdx.x; i < segN - seg0; i += 256) cur[i] = off[seg0 + i];
  __syncthreads();
  int start = off[seg0], end = off[segN];
  for (int i = start + threadIdx.x; i < end; i += 256) {
    int v = ebuf[i];
    int dloc = ((u32)v) >> SRCB;
    int pos = atomicAdd(&cur[dloc], 1);
    csrc[pos] = v & ((1 << SRCB) - 1);
  }
}

// ---------------- FC: h = x@W + b (bf16 out), na = h@an  [MFMA 16x16x32 bf16] ------------
__global__ __launch_bounds__(256, 2) void k_fc(
    const float* __restrict__ x, const float* __restrict__ W,
    const float* __restrict__ bias, const float* __restrict__ an,
    u16* __restrict__ h, float* __restrict__ na, int nrows) {
  __shared__ __align__(16) u16 sWT[128 * 136];
  int tid = threadIdx.x;
  int lane = tid & 63, w = tid >> 6;
  int cl = lane & 15, qg = lane >> 4;

  for (int i = tid * 4; i < 16384; i += 1024) {
    float4 v = *(const float4*)(W + i);
    int k = i >> 7, j = i & 127;
    sWT[(j + 0) * 136 + k] = f2bf(v.x);
    sWT[(j + 1) * 136 + k] = f2bf(v.y);
    sWT[(j + 2) * 136 + k] = f2bf(v.z);
    sWT[(j + 3) * 136 + k] = f2bf(v.w);
  }

  float anv[8], bv[8];
#pragma unroll
  for (int t = 0; t < 8; ++t) {
    anv[t] = an[t * 16 + cl];
    bv[t] = bias[t * 16 + cl];
  }

  int rbase = blockIdx.x * 128 + w * 32;
  bf16x8 afr[2][4];
#pragma unroll
  for (int g = 0; g < 2; ++g) {
    int r = rbase + g * 16 + cl;
    int rc = min(r, nrows - 1);
    const float* xp = x + (size_t)rc * 128 + qg * 8;
#pragma unroll
    for (int s = 0; s < 4; ++s) {
      float4 u0 = *(const float4*)(xp + s * 32);
      float4 u1 = *(const float4*)(xp + s * 32 + 4);
      bf16x8 a;
      a[0] = (short)f2bf(u0.x); a[1] = (short)f2bf(u0.y);
      a[2] = (short)f2bf(u0.z); a[3] = (short)f2bf(u0.w);
      a[4] = (short)f2bf(u1.x); a[5] = (short)f2bf(u1.y);
      a[6] = (short)f2bf(u1.z); a[7] = (short)f2bf(u1.w);
      afr[g][s] = a;
    }
  }
  __syncthreads();

  f32x4 acc[2][8];
#pragma unroll
  for (int g = 0; g < 2; ++g)
#pragma unroll
    for (int t = 0; t < 8; ++t) {
      acc[g][t][0] = 0.f; acc[g][t][1] = 0.f; acc[g][t][2] = 0.f; acc[g][t][3] = 0.f;
    }

#pragma unroll
  for (int t = 0; t < 8; ++t) {
    bf16x8 bfrg[4];
    const u16* bp = sWT + (t * 16 + cl) * 136 + qg * 8;
#pragma unroll
    for (int s = 0; s < 4; ++s) bfrg[s] = *(const bf16x8*)(bp + s * 32);
#pragma unroll
    for (int s = 0; s < 4; ++s) {
#pragma unroll
      for (int g = 0; g < 2; ++g)
        acc[g][t] = __builtin_amdgcn_mfma_f32_16x16x32_bf16(afr[g][s], bfrg[s], acc[g][t],
                                                            0, 0, 0);
    }
  }

  float pa[2][4];
#pragma unroll
  for (int g = 0; g < 2; ++g)
#pragma unroll
    for (int reg = 0; reg < 4; ++reg) pa[g][reg] = 0.f;
#pragma unroll
  for (int g = 0; g < 2; ++g)
#pragma unroll
    for (int t = 0; t < 8; ++t)
#pragma unroll
      for (int reg = 0; reg < 4; ++reg)
        pa[g][reg] = fmaf(acc[g][t][reg] + bv[t], anv[t], pa[g][reg]);
#pragma unroll
  for (int g = 0; g < 2; ++g)
#pragma unroll
    for (int reg = 0; reg < 4; ++reg) {
      float v = pa[g][reg];
      v += __shfl_xor(v, 1, 64);
      v += __shfl_xor(v, 2, 64);
      v += __shfl_xor(v, 4, 64);
      v += __shfl_xor(v, 8, 64);
      pa[g][reg] = v;
    }
  if (cl == 0) {
#pragma unroll
    for (int g = 0; g < 2; ++g)
#pragma unroll
      for (int reg = 0; reg < 4; ++reg) {
        int r = rbase + g * 16 + qg * 4 + reg;
        if (r < nrows) na[r] = pa[g][reg];
      }
  }

  __syncthreads();
  u16* st = sWT + w * 32 * 136;
#pragma unroll
  for (int g = 0; g < 2; ++g)
#pragma unroll
    for (int t = 0; t < 8; ++t)
#pragma unroll
      for (int reg = 0; reg < 4; ++reg)
        st[(g * 16 + qg * 4 + reg) * 136 + t * 16 + cl] = f2bf(acc[g][t][reg] + bv[t]);
#pragma unroll
  for (int it = 0; it < 8; ++it) {
    int idx = it * 64 + lane;
    int row = idx >> 4, c = idx & 15;
    u16x8 v = *(const u16x8*)(st + row * 136 + c * 8);
    int r = rbase + row;
    if (r < nrows) *(u16x8*)(h + (size_t)r * 128 + c * 8) = v;
  }
}

// ---------------- online softmax reductions ----------------
__device__ __forceinline__ void merge_write(float m, float s, float2* __restrict__ pairs) {
  for (int o = 1; o < 64; o <<= 1) {
    float om = __shfl_xor(m, o, 64), os = __shfl_xor(s, o, 64);
    float nm = fmaxf(m, om);
    s = s * __expf(m - nm) + os * __expf(om - nm);
    m = nm;
  }
  __shared__ float sm[4], ss[4];
  int t = threadIdx.x;
  if ((t & 63) == 0) { sm[t >> 6] = m; ss[t >> 6] = s; }
  __syncthreads();
  if (t == 0) {
    for (int k = 1; k < 4; ++k) {
      float nm = fmaxf(m, sm[k]);
      s = s * __expf(m - nm) + ss[k] * __expf(sm[k] - nm);
      m = nm;
    }
    pairs[blockIdx.x] = make_float2(m, s);
  }
}

__global__ void k_sm1(const float* __restrict__ na, const int* __restrict__ deg, int n,
                      float2* __restrict__ pairs) {
  float m = -1e30f, s = 0.f;
  int i = blockIdx.x * blockDim.x + threadIdx.x;
  int st = gridDim.x * blockDim.x;
  for (; i < n; i += st) {
    int d = deg[i];
    if (d > 0) {
      float xv = na[i];
      if (xv > m) { s *= __expf(m - xv); m = xv; }
      s += (float)d * __expf(xv - m);
    }
  }
  merge_write(m, s, pairs);
}

__global__ void k_sm2(const float* __restrict__ ea, const float* __restrict__ na,
                      const int* __restrict__ hs, const int* __restrict__ hd, int n,
                      float2* __restrict__ pairs) {
  float m = -1e30f, s = 0.f;
  int i = blockIdx.x * blockDim.x + threadIdx.x;
  int st = gridDim.x * blockDim.x;
  for (; i < n; i += st) {
    float xv = ea[hs[i]] + na[hd[i]];
    if (xv > m) { s *= __expf(m - xv); m = xv; }
    s += __expf(xv - m);
  }
  merge_write(m, s, pairs);
}

__global__ void k_smfin(const float2* __restrict__ pairs, int nb, float* __restrict__ out) {
  int t = threadIdx.x;
  float m = -1e30f, s = 0.f;
  for (int i = t; i < nb; i += 256) {
    float2 pr = pairs[i];
    float nm = fmaxf(m, pr.x);
    s = s * __expf(m - nm) + pr.y * __expf(pr.x - nm);
    m = nm;
  }
  for (int o = 1; o < 64; o <<= 1) {
    float om = __shfl_xor(m, o, 64), os = __shfl_xor(s, o, 64);
    float nm = fmaxf(m, om);
    s = s * __expf(m - nm) + os * __expf(om - nm);
    m = nm;
  }
  __shared__ float sm[4], ss[4];
  if ((t & 63) == 0) { sm[t >> 6] = m; ss[t >> 6] = s; }
  __syncthreads();
  if (t == 0) {
    for (int k = 1; k < 4; ++k) {
      float nm = fmaxf(m, sm[k]);
      s = s * __expf(m - nm) + ss[k] * __expf(sm[k] - nm);
      m = nm;
    }
    out[0] = m;
    out[1] = s;
  }
}

__global__ void k_wnode(const float* __restrict__ na, const float* __restrict__ sc,
                        float* __restrict__ w, int n) {
  float mx = sc[0];
  float iz = 1.0f / sc[1];
  int i = blockIdx.x * blockDim.x + threadIdx.x;
  if (i < n) w[i] = __expf(na[i] - mx) * iz;
}

__global__ void k_pe(const float* __restrict__ ea, const float* __restrict__ sc,
                     float* __restrict__ pe, int m) {
  float mx = sc[0];
  float iz = 1.0f / sc[1];
  int i = blockIdx.x * blockDim.x + threadIdx.x;
  if (i < m) pe[i] = __expf(ea[i] - mx) * iz;
}

// ---------------- segment sums (one wave/segment, 16B/lane, 4 edges/iter) ----------------
__global__ __launch_bounds__(256) void k_segA(
    const u16* __restrict__ h, const float* __restrict__ w,
    const int* __restrict__ csrc, const int* __restrict__ off,
    const float* __restrict__ ae, u16* __restrict__ he,
    float* __restrict__ ea, int m_count) {
  int wid = (blockIdx.x << 2) + (threadIdx.x >> 6);
  if (wid >= m_count) return;
  int lane = threadIdx.x & 63;
  int sub = lane >> 4, cl = lane & 15;
  int s = off[wid], t = off[wid + 1];
  float ax[8];
#pragma unroll
  for (int j = 0; j < 8; ++j) ax[j] = 0.f;
  for (int i = s + sub; i < t; i += 4) {
    int sr = csrc[i];
    float ww = w[sr];
    u16x8 v = *(const u16x8*)(h + (size_t)sr * 128 + cl * 8);
#pragma unroll
    for (int j = 0; j < 8; ++j) ax[j] = fmaf(ww, bf2f(v[j]), ax[j]);
  }
#pragma unroll
  for (int j = 0; j < 8; ++j) {
    ax[j] += __shfl_xor(ax[j], 16, 64);
    ax[j] += __shfl_xor(ax[j], 32, 64);
  }
  float4 a0 = *(const float4*)(ae + cl * 8);
  float4 a1 = *(const float4*)(ae + cl * 8 + 4);
  float pa = ax[0] * a0.x + ax[1] * a0.y + ax[2] * a0.z + ax[3] * a0.w +
             ax[4] * a1.x + ax[5] * a1.y + ax[6] * a1.z + ax[7] * a1.w;
  pa += __shfl_xor(pa, 1, 64);
  pa += __shfl_xor(pa, 2, 64);
  pa += __shfl_xor(pa, 4, 64);
  pa += __shfl_xor(pa, 8, 64);
  if (sub == 0) {
    u16x8 o;
#pragma unroll
    for (int j = 0; j < 8; ++j) o[j] = f2bf(ax[j]);
    *(u16x8*)(he + (size_t)wid * 128 + cl * 8) = o;
    if (cl == 0) ea[wid] = pa;
  }
}

__global__ __launch_bounds__(256) void k_segB(
    const u16* __restrict__ he, const float* __restrict__ pe,
    const float* __restrict__ na, const int* __restrict__ csrc,
    const int* __restrict__ off, float* __restrict__ y, int n_count, int relu) {
  int wid = (blockIdx.x << 2) + (threadIdx.x >> 6);
  if (wid >= n_count) return;
  int lane = threadIdx.x & 63;
  int sub = lane >> 4, cl = lane & 15;
  float rf = __expf(na[wid]);  // exp(ea+na-mx)/Z = pe[sr]*exp(na)
  int s = off[wid], t = off[wid + 1];
  float ax[8];
#pragma unroll
  for (int j = 0; j < 8; ++j) ax[j] = 0.f;
  for (int i = s + sub; i < t; i += 4) {
    int sr = csrc[i];
    float c = pe[sr];
    u16x8 v = *(const u16x8*)(he + (size_t)sr * 128 + cl * 8);
#pragma unroll
    for (int j = 0; j < 8; ++j) ax[j] = fmaf(c, bf2f(v[j]), ax[j]);
  }
#pragma unroll
  for (int j = 0; j < 8; ++j) {
    ax[j] += __shfl_xor(ax[j], 16, 64);
    ax[j] += __shfl_xor(ax[j], 32, 64);
    ax[j] *= rf;
    if (relu) ax[j] = fmaxf(ax[j], 0.f);
  }
  if (sub == 0) {
    float4 A = make_float4(ax[0], ax[1], ax[2], ax[3]);
    float4 B = make_float4(ax[4], ax[5], ax[6], ax[7]);
    *(float4*)(y + (size_t)wid * 128 + cl * 8) = A;
    *(float4*)(y + (size_t)wid * 128 + cl * 8 + 4) = B;
  }
}

// ---------------- host ----------------
extern "C" void kernel_launch(void* const* d_in, const int* in_sizes, int n_in,
                              void* d_out, int out_size, void* d_ws, size_t ws_size,
                              hipStream_t stream) {
  const int N = NCONST, M = MCONST, E = ECONST;
  const float* x = (const float*)d_in[0];
  const int* in_src = (const int*)d_in[1];
  const int* in_dst = (const int*)d_in[2];
  const int* has_src = (const int*)d_in[3];
  const int* has_dst = (const int*)d_in[4];
  const float* W1 = (const float*)d_in[5];
  const float* b1 = (const float*)d_in[6];
  const float* an1 = (const float*)d_in[7];
  const float* ae1 = (const float*)d_in[8];
  const float* W2 = (const float*)d_in[9];
  const float* b2 = (const float*)d_in[10];
  const float* an2 = (const float*)d_in[11];
  const float* ae2 = (const float*)d_in[12];

  const int NCH_M = (MCONST + HCH - 1) / HCH;  // 2
  const int NCH_N = (NCONST + HCH - 1) / HCH;  // 7
  const size_t PARTIAL_BYTES = (size_t)NCH_N * HBC * HCH * 4;  // 14.7 MB

  char* p = (char*)d_ws;
  auto alloc = [&](size_t bytes) {
    char* q = p;
    p += (bytes + 255) & ~(size_t)255;
    return q;
  };
  u16* h = (u16*)alloc((size_t)N * 128 * 2);
  u16* he = (u16*)alloc((size_t)M * 128 * 2);
  float* na = (float*)alloc((size_t)N * 4);
  float* ea = (float*)alloc((size_t)M * 4);
  float* wn = (float*)alloc((size_t)N * 4);
  float* pe = (float*)alloc((size_t)M * 4);
  int* off_in = (int*)alloc((size_t)(M + 1) * 4);
  int* off_has = (int*)alloc((size_t)(N + 1) * 4);
  int* csrc_in = (int*)alloc((size_t)E * 4);
  int* csrc_has = (int*)alloc((size_t)E * 4);
  int* partial = (int*)alloc(PARTIAL_BYTES);  // unions with ebuf (disjoint lifetime)
  int* ebuf = partial;
  int* bb_in = (int*)alloc((size_t)PBLK * NBK_IN * 4);
  int* bb_has = (int*)alloc((size_t)PBLK * NBK_HAS * 4);
  int* bsum = (int*)alloc(256 * 4);
  float2* pairs = (float2*)alloc(256 * 8);
  float* scal = (float*)alloc(64);
  int* cnt_in = (int*)alloc((size_t)M * 4);
  int* cnt_has = (int*)alloc((size_t)N * 4);
  int* deg_src = (int*)alloc((size_t)N * 4);
  if ((size_t)(p - (char*)d_ws) > ws_size) return;  // insufficient workspace

  // fine histograms (atomic-free)
  k_hpart<<<dim3(HBC, NCH_M), 256, 0, stream>>>(in_dst, E, partial);
  k_hred<<<(M + 255) / 256, 256, 0, stream>>>(partial, M, cnt_in);
  k_hpart<<<dim3(HBC, NCH_N), 256, 0, stream>>>(has_dst, E, partial);
  k_hred<<<(N + 255) / 256, 256, 0, stream>>>(partial, N, cnt_has);
  k_hpart<<<dim3(HBC, NCH_N), 256, 0, stream>>>(in_src, E, partial);
  k_hred<<<(N + 255) / 256, 256, 0, stream>>>(partial, N, deg_src);

  int nb_in = (M + 1023) / 1024;
  k_scan1<<<nb_in, 256, 0, stream>>>(cnt_in, M, off_in, bsum);
  k_scan2<<<1, 256, 0, stream>>>(bsum, nb_in);
  k_scan3<<<256, 256, 0, stream>>>(off_in, M, bsum);
  int nb_has = (N + 1023) / 1024;
  k_scan1<<<nb_has, 256, 0, stream>>>(cnt_has, N, off_has, bsum);
  k_scan2<<<1, 256, 0, stream>>>(bsum, nb_has);
  k_scan3<<<512, 256, 0, stream>>>(off_has, N, bsum);

  // scatter v3 (atomic-free partition)
  k_coarse<<<PBLK, 256, 0, stream>>>(in_dst, has_dst, bb_in, bb_has);
  k_colscan<<<NBK_IN, 256, 0, stream>>>(bb_in, NBK_IN, off_in, SHB_IN, M);
  k_colscan<<<NBK_HAS, 256, 0, stream>>>(bb_has, NBK_HAS, off_has, SHB_HAS, N);
  k_stage<NBK_IN, SHB_IN, SRCB_IN><<<PBLK, 256, 0, stream>>>(in_dst, in_src, bb_in, ebuf);
  k_place<SHB_IN, SRCB_IN><<<NBK_IN, 256, 0, stream>>>(off_in, M, ebuf, csrc_in);
  k_stage<NBK_HAS, SHB_HAS, SRCB_HAS><<<PBLK, 256, 0, stream>>>(has_dst, has_src, bb_has,
                                                                ebuf);
  k_place<SHB_HAS, SRCB_HAS><<<NBK_HAS, 256, 0, stream>>>(off_has, N, ebuf, csrc_has);

  auto layer = [&](const float* xin, const float* W, const float* b, const float* an_,
                   const float* ae_, float* yout, int relu) {
    k_fc<<<(N + 127) / 128, 256, 0, stream>>>(xin, W, b, an_, h, na, N);
    k_sm1<<<256, 256, 0, stream>>>(na, deg_src, N, pairs);
    k_smfin<<<1, 256, 0, stream>>>(pairs, 256, scal);
    k_wnode<<<(N + 255) / 256, 256, 0, stream>>>(na, scal, wn, N);
    k_segA<<<(M + 3) / 4, 256, 0, stream>>>(h, wn, csrc_in, off_in, ae_, he, ea, M);
    k_sm2<<<256, 256, 0, stream>>>(ea, na, has_src, has_dst, E, pairs);
    k_smfin<<<1, 256, 0, stream>>>(pairs, 256, scal + 2);
    k_pe<<<(M + 255) / 256, 256, 0, stream>>>(ea, scal + 2, pe, M);
    k_segB<<<(N + 3) / 4, 256, 0, stream>>>(he, pe, na, csrc_has, off_has, yout, N, relu);
  };

  layer(x, W1, b1, an1, ae1, (float*)d_out, 1);
  layer((const float*)d_out, W2, b2, an2, ae2, (float*)d_out, 0);
}

// Round 9
// 481.544 us; speedup vs baseline: 3.8530x; 1.1066x over previous
//
#include <hip/hip_runtime.h>
#include <hip/hip_bf16.h>
#include <math.h>

// HGAT: 2-layer hypergraph attention. N nodes, M hyperedges, E incidence edges, D=128.
// R9: tail reduction. segA (63us) is at its random-gather floor (409MB logical @ ~6.5TB/s
// effective); remaining 407us was histogram re-reads + ~37 dispatch overheads.
// - k_hpart2: one launch, 128KB-LDS chunks (M=1 chunk, N=4), in_src hist DROPPED
//   (sm1 now a single online pass over E: k_sm1e). k_hred fused into k_scan1d.
// - wnode/pe fused into segA/segB (inline exp; VALU at 23% has headroom).
// - scan chains merged across M/N via blockIdx.y.
// - layer-1 output stored bf16 in d_out's bytes (only fc2 reads it; final fp32 result
//   overwrites later). fc templated on input dtype.
// Scatter v3 (R8), MFMA fc (R4), bf16 rows (R3) unchanged. 25 dispatches (was 37).

typedef unsigned int u32;
typedef unsigned short u16;
typedef u16 u16x8 __attribute__((ext_vector_type(8)));
typedef short bf16x8 __attribute__((ext_vector_type(8)));
typedef float f32x4 __attribute__((ext_vector_type(4)));

#define NCONST 100000
#define MCONST 20000
#define ECONST 1600000
#define HCH2 32768  // histogram chunk (ints) = 128KB LDS; M fits in 1 chunk, N in 4
#define HBC 32      // blocks per chunk
#define NCH_N 4     // ceil(N / HCH2)

#define PBLK 256        // partition blocks (1 chunk each)
#define PT 6250         // edges per partition chunk (E/PBLK)
#define SHB_IN 6        // coarse bucket shift, in-direction (bucket = 64 segs)
#define NBK_IN 313      // ceil(M / 64)
#define SRCB_IN 17      // src bits (in_src < 100000 < 2^17)
#define SHB_HAS 8       // coarse bucket shift, has-direction (bucket = 256 segs)
#define NBK_HAS 391     // ceil(N / 256)
#define SRCB_HAS 15     // src bits (has_src < 20000 < 2^15)

__device__ __forceinline__ u16 f2bf(float f) {  // RNE
  u32 u = __float_as_uint(f);
  u += 0x7FFFu + ((u >> 16) & 1u);
  return (u16)(u >> 16);
}
__device__ __forceinline__ float bf2f(u16 b) {
  return __uint_as_float(((u32)b) << 16);
}

// ---------------- histograms: one launch, LDS-private, no global atomics ----------------
// grid (HBC, 1+NCH_N): y=0 -> in_dst chunk 0 (M<HCH2); y=1..NCH_N -> has_dst chunk y-1.
__global__ __launch_bounds__(256) void k_hpart2(const int* __restrict__ in_dst,
                                                const int* __restrict__ has_dst,
                                                int* __restrict__ partial) {
  __shared__ int hc[HCH2];
  int y = blockIdx.y;
  const int* __restrict__ arr = (y == 0) ? in_dst : has_dst;
  int lo = (y == 0) ? 0 : (y - 1) * HCH2;
  for (int i = threadIdx.x; i < HCH2; i += 256) hc[i] = 0;
  __syncthreads();
  int stride = gridDim.x * 256;
  int n4 = ECONST >> 2;
  const int4* a4 = (const int4*)arr;
  for (int i = blockIdx.x * 256 + threadIdx.x; i < n4; i += stride) {
    int4 v = a4[i];
    u32 a = (u32)(v.x - lo), b = (u32)(v.y - lo), c = (u32)(v.z - lo), d = (u32)(v.w - lo);
    if (a < HCH2) atomicAdd(&hc[a], 1);
    if (b < HCH2) atomicAdd(&hc[b], 1);
    if (c < HCH2) atomicAdd(&hc[c], 1);
    if (d < HCH2) atomicAdd(&hc[d], 1);
  }
  __syncthreads();
  int* out = partial + ((size_t)y * HBC + blockIdx.x) * HCH2;
  for (int i = threadIdx.x; i < HCH2; i += 256) out[i] = hc[i];
}

// ---------------- scans (M and N chains merged via blockIdx.y) ----------------
// counts read directly from partial: cnt[j] = sum_b partial[(yoff + (j>>15))*HBC + b][j&32767]
__global__ void k_scan1d(const int* __restrict__ partial, int nM, int nN,
                         int* __restrict__ off_in, int* __restrict__ off_has,
                         int* __restrict__ bsum) {
  __shared__ int sd[256];
  int y = blockIdx.y;
  int n = y ? nN : nM;
  int yoff = y;  // y=0 -> partial row 0 (M); y=1 -> rows 1..4 (N chunks)
  int* off = y ? off_has : off_in;
  int* bs = bsum + y * 128;
  int t = threadIdx.x;
  int base = blockIdx.x * 1024 + t * 4;
  int v[4];
#pragma unroll
  for (int k = 0; k < 4; ++k) {
    int j = base + k;
    int s = 0;
    if (j < n) {
      int chunk = j >> 15;
      int jl = j & (HCH2 - 1);
      const int* p = partial + ((size_t)(yoff + chunk) * HBC) * HCH2 + jl;
#pragma unroll
      for (int b = 0; b < HBC; ++b) s += p[(size_t)b * HCH2];
    }
    v[k] = s;
  }
  v[1] += v[0]; v[2] += v[1]; v[3] += v[2];
  int tot = v[3];
  sd[t] = tot;
  __syncthreads();
  for (int o = 1; o < 256; o <<= 1) {
    int x = (t >= o) ? sd[t - o] : 0;
    __syncthreads();
    sd[t] += x;
    __syncthreads();
  }
  int excl = sd[t] - tot;
#pragma unroll
  for (int k = 0; k < 4; ++k)
    if (base + k < n) off[base + k + 1] = v[k] + excl;
  if (t == 255) bs[blockIdx.x] = sd[255];
}

__global__ void k_scan2d(int* __restrict__ bsum, int nbM, int nbN) {
  __shared__ int sd[256];
  int* bs = bsum + blockIdx.x * 128;
  int nb = blockIdx.x ? nbN : nbM;
  int t = threadIdx.x;
  int v = (t < nb) ? bs[t] : 0;
  sd[t] = v;
  __syncthreads();
  for (int o = 1; o < 256; o <<= 1) {
    int x = (t >= o) ? sd[t - o] : 0;
    __syncthreads();
    sd[t] += x;
    __syncthreads();
  }
  if (t < nb) bs[t] = sd[t] - v;  // exclusive
}

__global__ void k_scan3d(int* __restrict__ off_in, int* __restrict__ off_has,
                         const int* __restrict__ bsum, int nM, int nN) {
  int y = blockIdx.y;
  int* off = y ? off_has : off_in;
  const int* bs = bsum + y * 128;
  int n = y ? nN : nM;
  int i = blockIdx.x * blockDim.x + threadIdx.x;
  int st = gridDim.x * blockDim.x;
  if (blockIdx.x == 0 && threadIdx.x == 0) off[0] = 0;
  for (; i < n; i += st) off[i + 1] += bs[i >> 10];
}

// ---------------- scatter v3: atomic-free LDS-staged partition (R8) ----------------
__global__ __launch_bounds__(256) void k_coarse(const int* __restrict__ in_dst,
                                                const int* __restrict__ has_dst,
                                                int* __restrict__ bb_in,
                                                int* __restrict__ bb_has) {
  __shared__ int h1[NBK_IN];
  __shared__ int h2[NBK_HAS];
  for (int i = threadIdx.x; i < NBK_IN; i += 256) h1[i] = 0;
  for (int i = threadIdx.x; i < NBK_HAS; i += 256) h2[i] = 0;
  __syncthreads();
  int c0 = blockIdx.x * PT, c1 = min(c0 + PT, ECONST);
  for (int i = c0 + threadIdx.x; i < c1; i += 256) {
    atomicAdd(&h1[in_dst[i] >> SHB_IN], 1);
    atomicAdd(&h2[has_dst[i] >> SHB_HAS], 1);
  }
  __syncthreads();
  int* o1 = bb_in + (size_t)blockIdx.x * NBK_IN;
  for (int i = threadIdx.x; i < NBK_IN; i += 256) o1[i] = h1[i];
  int* o2 = bb_has + (size_t)blockIdx.x * NBK_HAS;
  for (int i = threadIdx.x; i < NBK_HAS; i += 256) o2[i] = h2[i];
}

__global__ __launch_bounds__(256) void k_colscan(int* __restrict__ bb, int nbuk,
                                                 const int* __restrict__ off, int shb,
                                                 int segs) {
  __shared__ int sd[256];
  int b = blockIdx.x;
  int t = threadIdx.x;
  int v = bb[(size_t)t * nbuk + b];
  sd[t] = v;
  __syncthreads();
  for (int o = 1; o < 256; o <<= 1) {
    int x = (t >= o) ? sd[t - o] : 0;
    __syncthreads();
    sd[t] += x;
    __syncthreads();
  }
  bb[(size_t)t * nbuk + b] = sd[t] - v + off[min(b << shb, segs)];
}

template <int NBUK, int SHB, int SRCB>
__global__ __launch_bounds__(256) void k_stage(const int* __restrict__ dst,
                                               const int* __restrict__ srcv,
                                               const int* __restrict__ bb,
                                               int* __restrict__ ebuf) {
  __shared__ int hist[NBUK];   // later reused as rank cursor
  __shared__ int loff[NBUK];
  __shared__ int gbase[NBUK];
  __shared__ int stage[PT];
  __shared__ int sd[256];
  int t = threadIdx.x;
  for (int i = t; i < NBUK; i += 256) hist[i] = 0;
  __syncthreads();
  int c0 = blockIdx.x * PT, c1 = min(c0 + PT, ECONST);
  for (int i = c0 + t; i < c1; i += 256) atomicAdd(&hist[dst[i] >> SHB], 1);
  __syncthreads();
  {
    int v0 = (2 * t < NBUK) ? hist[2 * t] : 0;
    int v1 = (2 * t + 1 < NBUK) ? hist[2 * t + 1] : 0;
    sd[t] = v0 + v1;
    __syncthreads();
    for (int o = 1; o < 256; o <<= 1) {
      int x = (t >= o) ? sd[t - o] : 0;
      __syncthreads();
      sd[t] += x;
      __syncthreads();
    }
    int excl = sd[t] - (v0 + v1);
    if (2 * t < NBUK) loff[2 * t] = excl;
    if (2 * t + 1 < NBUK) loff[2 * t + 1] = excl + v0;
  }
  __syncthreads();
  for (int i = t; i < NBUK; i += 256) {
    gbase[i] = bb[(size_t)blockIdx.x * NBUK + i];
    hist[i] = loff[i];  // cursor
  }
  __syncthreads();
  for (int i = c0 + t; i < c1; i += 256) {
    int d = dst[i], s = srcv[i];
    int b = d >> SHB;
    int r = atomicAdd(&hist[b], 1);
    stage[r] = (b << 23) | ((d & ((1 << SHB) - 1)) << SRCB) | s;
  }
  __syncthreads();
  int tot = c1 - c0;
  for (int i = t; i < tot; i += 256) {
    int v = stage[i];
    int b = ((u32)v) >> 23;
    ebuf[gbase[b] + (i - loff[b])] = v & ((1 << 23) - 1);
  }
}

template <int SHB, int SRCB>
__global__ __launch_bounds__(256) void k_place(const int* __restrict__ off, int segs,
                                               const int* __restrict__ ebuf,
                                               int* __restrict__ csrc) {
  const int NSEG = 1 << SHB;
  __shared__ int cur[NSEG];
  int seg0 = blockIdx.x << SHB;
  if (seg0 >= segs) return;
  int segN = min(seg0 + NSEG, segs);
  for (int i = threadIdx.x; i < segN - seg0; i += 256) cur[i] = off[seg0 + i];
  __syncthreads();
  int start = off[seg0], end = off[segN];
  for (int i = start + threadIdx.x; i < end; i += 256) {
    int v = ebuf[i];
    int dloc = ((u32)v) >> SRCB;
    int pos = atomicAdd(&cur[dloc], 1);
    csrc[pos] = v & ((1 << SRCB) - 1);
  }
}

// ---------------- FC: h = x@W + b (bf16 out), na = h@an  [MFMA 16x16x32 bf16] ------------
// IT = float (layer 1, converts to bf16 in-register) or u16 (layer 2, bf16 bits direct).
template <typename IT>
__global__ __launch_bounds__(256, 2) void k_fc(
    const IT* __restrict__ x, const float* __restrict__ W,
    const float* __restrict__ bias, const float* __restrict__ an,
    u16* __restrict__ h, float* __restrict__ na, int nrows) {
  __shared__ __align__(16) u16 sWT[128 * 136];
  int tid = threadIdx.x;
  int lane = tid & 63, w = tid >> 6;
  int cl = lane & 15, qg = lane >> 4;

  for (int i = tid * 4; i < 16384; i += 1024) {
    float4 v = *(const float4*)(W + i);
    int k = i >> 7, j = i & 127;
    sWT[(j + 0) * 136 + k] = f2bf(v.x);
    sWT[(j + 1) * 136 + k] = f2bf(v.y);
    sWT[(j + 2) * 136 + k] = f2bf(v.z);
    sWT[(j + 3) * 136 + k] = f2bf(v.w);
  }

  float anv[8], bv[8];
#pragma unroll
  for (int t = 0; t < 8; ++t) {
    anv[t] = an[t * 16 + cl];
    bv[t] = bias[t * 16 + cl];
  }

  int rbase = blockIdx.x * 128 + w * 32;
  bf16x8 afr[2][4];
#pragma unroll
  for (int g = 0; g < 2; ++g) {
    int r = rbase + g * 16 + cl;
    int rc = min(r, nrows - 1);
    const IT* xp = x + (size_t)rc * 128 + qg * 8;
#pragma unroll
    for (int s = 0; s < 4; ++s) {
      if constexpr (sizeof(IT) == 4) {
        float4 u0 = *(const float4*)(xp + s * 32);
        float4 u1 = *(const float4*)(xp + s * 32 + 4);
        bf16x8 a;
        a[0] = (short)f2bf(u0.x); a[1] = (short)f2bf(u0.y);
        a[2] = (short)f2bf(u0.z); a[3] = (short)f2bf(u0.w);
        a[4] = (short)f2bf(u1.x); a[5] = (short)f2bf(u1.y);
        a[6] = (short)f2bf(u1.z); a[7] = (short)f2bf(u1.w);
        afr[g][s] = a;
      } else {
        afr[g][s] = *(const bf16x8*)(xp + s * 32);
      }
    }
  }
  __syncthreads();

  f32x4 acc[2][8];
#pragma unroll
  for (int g = 0; g < 2; ++g)
#pragma unroll
    for (int t = 0; t < 8; ++t) {
      acc[g][t][0] = 0.f; acc[g][t][1] = 0.f; acc[g][t][2] = 0.f; acc[g][t][3] = 0.f;
    }

#pragma unroll
  for (int t = 0; t < 8; ++t) {
    bf16x8 bfrg[4];
    const u16* bp = sWT + (t * 16 + cl) * 136 + qg * 8;
#pragma unroll
    for (int s = 0; s < 4; ++s) bfrg[s] = *(const bf16x8*)(bp + s * 32);
#pragma unroll
    for (int s = 0; s < 4; ++s) {
#pragma unroll
      for (int g = 0; g < 2; ++g)
        acc[g][t] = __builtin_amdgcn_mfma_f32_16x16x32_bf16(afr[g][s], bfrg[s], acc[g][t],
                                                            0, 0, 0);
    }
  }

  float pa[2][4];
#pragma unroll
  for (int g = 0; g < 2; ++g)
#pragma unroll
    for (int reg = 0; reg < 4; ++reg) pa[g][reg] = 0.f;
#pragma unroll
  for (int g = 0; g < 2; ++g)
#pragma unroll
    for (int t = 0; t < 8; ++t)
#pragma unroll
      for (int reg = 0; reg < 4; ++reg)
        pa[g][reg] = fmaf(acc[g][t][reg] + bv[t], anv[t], pa[g][reg]);
#pragma unroll
  for (int g = 0; g < 2; ++g)
#pragma unroll
    for (int reg = 0; reg < 4; ++reg) {
      float v = pa[g][reg];
      v += __shfl_xor(v, 1, 64);
      v += __shfl_xor(v, 2, 64);
      v += __shfl_xor(v, 4, 64);
      v += __shfl_xor(v, 8, 64);
      pa[g][reg] = v;
    }
  if (cl == 0) {
#pragma unroll
    for (int g = 0; g < 2; ++g)
#pragma unroll
      for (int reg = 0; reg < 4; ++reg) {
        int r = rbase + g * 16 + qg * 4 + reg;
        if (r < nrows) na[r] = pa[g][reg];
      }
  }

  __syncthreads();
  u16* st = sWT + w * 32 * 136;
#pragma unroll
  for (int g = 0; g < 2; ++g)
#pragma unroll
    for (int t = 0; t < 8; ++t)
#pragma unroll
      for (int reg = 0; reg < 4; ++reg)
        st[(g * 16 + qg * 4 + reg) * 136 + t * 16 + cl] = f2bf(acc[g][t][reg] + bv[t]);
#pragma unroll
  for (int it = 0; it < 8; ++it) {
    int idx = it * 64 + lane;
    int row = idx >> 4, c = idx & 15;
    u16x8 v = *(const u16x8*)(st + row * 136 + c * 8);
    int r = rbase + row;
    if (r < nrows) *(u16x8*)(h + (size_t)r * 128 + c * 8) = v;
  }
}

// ---------------- online softmax reductions ----------------
__device__ __forceinline__ void merge_write(float m, float s, float2* __restrict__ pairs) {
  for (int o = 1; o < 64; o <<= 1) {
    float om = __shfl_xor(m, o, 64), os = __shfl_xor(s, o, 64);
    float nm = fmaxf(m, om);
    s = s * __expf(m - nm) + os * __expf(om - nm);
    m = nm;
  }
  __shared__ float sm[4], ss[4];
  int t = threadIdx.x;
  if ((t & 63) == 0) { sm[t >> 6] = m; ss[t >> 6] = s; }
  __syncthreads();
  if (t == 0) {
    for (int k = 1; k < 4; ++k) {
      float nm = fmaxf(m, sm[k]);
      s = s * __expf(m - nm) + ss[k] * __expf(sm[k] - nm);
      m = nm;
    }
    pairs[blockIdx.x] = make_float2(m, s);
  }
}

// softmax1: single online pass over E (e = na[in_src[i]])
__global__ void k_sm1e(const float* __restrict__ na, const int* __restrict__ src, int n,
                       float2* __restrict__ pairs) {
  float m = -1e30f, s = 0.f;
  int i = blockIdx.x * blockDim.x + threadIdx.x;
  int st = gridDim.x * blockDim.x;
  for (; i < n; i += st) {
    float xv = na[src[i]];
    if (xv > m) { s *= __expf(m - xv); m = xv; }
    s += __expf(xv - m);
  }
  merge_write(m, s, pairs);
}

// softmax2 single online pass over E
__global__ void k_sm2(const float* __restrict__ ea, const float* __restrict__ na,
                      const int* __restrict__ hs, const int* __restrict__ hd, int n,
                      float2* __restrict__ pairs) {
  float m = -1e30f, s = 0.f;
  int i = blockIdx.x * blockDim.x + threadIdx.x;
  int st = gridDim.x * blockDim.x;
  for (; i < n; i += st) {
    float xv = ea[hs[i]] + na[hd[i]];
    if (xv > m) { s *= __expf(m - xv); m = xv; }
    s += __expf(xv - m);
  }
  merge_write(m, s, pairs);
}

__global__ void k_smfin(const float2* __restrict__ pairs, int nb, float* __restrict__ out) {
  int t = threadIdx.x;
  float m = -1e30f, s = 0.f;
  for (int i = t; i < nb; i += 256) {
    float2 pr = pairs[i];
    float nm = fmaxf(m, pr.x);
    s = s * __expf(m - nm) + pr.y * __expf(pr.x - nm);
    m = nm;
  }
  for (int o = 1; o < 64; o <<= 1) {
    float om = __shfl_xor(m, o, 64), os = __shfl_xor(s, o, 64);
    float nm = fmaxf(m, om);
    s = s * __expf(m - nm) + os * __expf(om - nm);
    m = nm;
  }
  __shared__ float sm[4], ss[4];
  if ((t & 63) == 0) { sm[t >> 6] = m; ss[t >> 6] = s; }
  __syncthreads();
  if (t == 0) {
    for (int k = 1; k < 4; ++k) {
      float nm = fmaxf(m, sm[k]);
      s = s * __expf(m - nm) + ss[k] * __expf(sm[k] - nm);
      m = nm;
    }
    out[0] = m;
    out[1] = s;
  }
}

// ---------------- segment sums (one wave/segment, 16B/lane, 4 edges/iter) ----------------
// wnode fused: w[sr] = exp(na[sr]-mx1)*iz1 computed inline.
__global__ __launch_bounds__(256) void k_segA(
    const u16* __restrict__ h, const float* __restrict__ na,
    const float* __restrict__ scal, const int* __restrict__ csrc,
    const int* __restrict__ off, const float* __restrict__ ae, u16* __restrict__ he,
    float* __restrict__ ea, int m_count) {
  int wid = (blockIdx.x << 2) + (threadIdx.x >> 6);
  if (wid >= m_count) return;
  float mx = scal[0];
  float iz = 1.0f / scal[1];
  int lane = threadIdx.x & 63;
  int sub = lane >> 4, cl = lane & 15;
  int s = off[wid], t = off[wid + 1];
  float ax[8];
#pragma unroll
  for (int j = 0; j < 8; ++j) ax[j] = 0.f;
  for (int i = s + sub; i < t; i += 4) {
    int sr = csrc[i];
    float ww = __expf(na[sr] - mx) * iz;
    u16x8 v = *(const u16x8*)(h + (size_t)sr * 128 + cl * 8);
#pragma unroll
    for (int j = 0; j < 8; ++j) ax[j] = fmaf(ww, bf2f(v[j]), ax[j]);
  }
#pragma unroll
  for (int j = 0; j < 8; ++j) {
    ax[j] += __shfl_xor(ax[j], 16, 64);
    ax[j] += __shfl_xor(ax[j], 32, 64);
  }
  float4 a0 = *(const float4*)(ae + cl * 8);
  float4 a1 = *(const float4*)(ae + cl * 8 + 4);
  float pa = ax[0] * a0.x + ax[1] * a0.y + ax[2] * a0.z + ax[3] * a0.w +
             ax[4] * a1.x + ax[5] * a1.y + ax[6] * a1.z + ax[7] * a1.w;
  pa += __shfl_xor(pa, 1, 64);
  pa += __shfl_xor(pa, 2, 64);
  pa += __shfl_xor(pa, 4, 64);
  pa += __shfl_xor(pa, 8, 64);
  if (sub == 0) {
    u16x8 o;
#pragma unroll
    for (int j = 0; j < 8; ++j) o[j] = f2bf(ax[j]);
    *(u16x8*)(he + (size_t)wid * 128 + cl * 8) = o;
    if (cl == 0) ea[wid] = pa;
  }
}

// pe fused: coeff = exp(ea[sr]+na[wid]-mx2)*iz2. L1: relu + bf16 out; else fp32 out.
template <int L1>
__global__ __launch_bounds__(256) void k_segB(
    const u16* __restrict__ he, const float* __restrict__ ea,
    const float* __restrict__ na, const float* __restrict__ scal,
    const int* __restrict__ csrc, const int* __restrict__ off,
    void* __restrict__ yout, int n_count) {
  int wid = (blockIdx.x << 2) + (threadIdx.x >> 6);
  if (wid >= n_count) return;
  float mx2 = scal[2];
  float iz2 = 1.0f / scal[3];
  int lane = threadIdx.x & 63;
  int sub = lane >> 4, cl = lane & 15;
  float nav = na[wid];
  int s = off[wid], t = off[wid + 1];
  float ax[8];
#pragma unroll
  for (int j = 0; j < 8; ++j) ax[j] = 0.f;
  for (int i = s + sub; i < t; i += 4) {
    int sr = csrc[i];
    float c = __expf(ea[sr] + nav - mx2) * iz2;
    u16x8 v = *(const u16x8*)(he + (size_t)sr * 128 + cl * 8);
#pragma unroll
    for (int j = 0; j < 8; ++j) ax[j] = fmaf(c, bf2f(v[j]), ax[j]);
  }
#pragma unroll
  for (int j = 0; j < 8; ++j) {
    ax[j] += __shfl_xor(ax[j], 16, 64);
    ax[j] += __shfl_xor(ax[j], 32, 64);
    if (L1) ax[j] = fmaxf(ax[j], 0.f);
  }
  if (sub == 0) {
    if (L1) {
      u16x8 o;
#pragma unroll
      for (int j = 0; j < 8; ++j) o[j] = f2bf(ax[j]);
      *(u16x8*)((u16*)yout + (size_t)wid * 128 + cl * 8) = o;
    } else {
      float4 A = make_float4(ax[0], ax[1], ax[2], ax[3]);
      float4 B = make_float4(ax[4], ax[5], ax[6], ax[7]);
      float* y = (float*)yout;
      *(float4*)(y + (size_t)wid * 128 + cl * 8) = A;
      *(float4*)(y + (size_t)wid * 128 + cl * 8 + 4) = B;
    }
  }
}

// ---------------- host ----------------
extern "C" void kernel_launch(void* const* d_in, const int* in_sizes, int n_in,
                              void* d_out, int out_size, void* d_ws, size_t ws_size,
                              hipStream_t stream) {
  const int N = NCONST, M = MCONST, E = ECONST;
  const float* x = (const float*)d_in[0];
  const int* in_src = (const int*)d_in[1];
  const int* in_dst = (const int*)d_in[2];
  const int* has_src = (const int*)d_in[3];
  const int* has_dst = (const int*)d_in[4];
  const float* W1 = (const float*)d_in[5];
  const float* b1 = (const float*)d_in[6];
  const float* an1 = (const float*)d_in[7];
  const float* ae1 = (const float*)d_in[8];
  const float* W2 = (const float*)d_in[9];
  const float* b2 = (const float*)d_in[10];
  const float* an2 = (const float*)d_in[11];
  const float* ae2 = (const float*)d_in[12];

  const size_t PARTIAL_BYTES = (size_t)(1 + NCH_N) * HBC * HCH2 * 4;  // 21 MB

  char* p = (char*)d_ws;
  auto alloc = [&](size_t bytes) {
    char* q = p;
    p += (bytes + 255) & ~(size_t)255;
    return q;
  };
  u16* h = (u16*)alloc((size_t)N * 128 * 2);
  u16* he = (u16*)alloc((size_t)M * 128 * 2);
  float* na = (float*)alloc((size_t)N * 4);
  float* ea = (float*)alloc((size_t)M * 4);
  int* off_in = (int*)alloc((size_t)(M + 1) * 4);
  int* off_has = (int*)alloc((size_t)(N + 1) * 4);
  int* csrc_in = (int*)alloc((size_t)E * 4);
  int* csrc_has = (int*)alloc((size_t)E * 4);
  int* partial = (int*)alloc(PARTIAL_BYTES);  // unions with ebuf (disjoint lifetime)
  int* ebuf = partial;
  int* bb_in = (int*)alloc((size_t)PBLK * NBK_IN * 4);
  int* bb_has = (int*)alloc((size_t)PBLK * NBK_HAS * 4);
  int* bsum = (int*)alloc(256 * 4);
  float2* pairs = (float2*)alloc(512 * 8);
  float* scal = (float*)alloc(64);
  if ((size_t)(p - (char*)d_ws) > ws_size) return;  // insufficient workspace

  u16* y1b = (u16*)d_out;  // layer-1 bf16 output staged in d_out bytes (fc2-only reader;
                           // overwritten by final fp32 result in segB<0>)

  // histograms (one launch) + merged scans
  k_hpart2<<<dim3(HBC, 1 + NCH_N), 256, 0, stream>>>(in_dst, has_dst, partial);
  int nbM = (M + 1023) / 1024, nbN = (N + 1023) / 1024;
  k_scan1d<<<dim3(nbN, 2), 256, 0, stream>>>(partial, M, N, off_in, off_has, bsum);
  k_scan2d<<<2, 256, 0, stream>>>(bsum, nbM, nbN);
  k_scan3d<<<dim3(512, 2), 256, 0, stream>>>(off_in, off_has, bsum, M, N);

  // scatter v3 (atomic-free partition)
  k_coarse<<<PBLK, 256, 0, stream>>>(in_dst, has_dst, bb_in, bb_has);
  k_colscan<<<NBK_IN, 256, 0, stream>>>(bb_in, NBK_IN, off_in, SHB_IN, M);
  k_colscan<<<NBK_HAS, 256, 0, stream>>>(bb_has, NBK_HAS, off_has, SHB_HAS, N);
  k_stage<NBK_IN, SHB_IN, SRCB_IN><<<PBLK, 256, 0, stream>>>(in_dst, in_src, bb_in, ebuf);
  k_place<SHB_IN, SRCB_IN><<<NBK_IN, 256, 0, stream>>>(off_in, M, ebuf, csrc_in);
  k_stage<NBK_HAS, SHB_HAS, SRCB_HAS><<<PBLK, 256, 0, stream>>>(has_dst, has_src, bb_has,
                                                                ebuf);
  k_place<SHB_HAS, SRCB_HAS><<<NBK_HAS, 256, 0, stream>>>(off_has, N, ebuf, csrc_has);

  auto layer = [&](auto xin, const float* W, const float* b, const float* an_,
                   const float* ae_, auto seg_b) {
    using IT = typename std::remove_pointer<decltype(xin)>::type;
    k_fc<typename std::remove_const<IT>::type>
        <<<(N + 127) / 128, 256, 0, stream>>>(xin, W, b, an_, h, na, N);
    k_sm1e<<<512, 256, 0, stream>>>(na, in_src, E, pairs);
    k_smfin<<<1, 256, 0, stream>>>(pairs, 512, scal);
    k_segA<<<(M + 3) / 4, 256, 0, stream>>>(h, na, scal, csrc_in, off_in, ae_, he, ea, M);
    k_sm2<<<256, 256, 0, stream>>>(ea, na, has_src, has_dst, E, pairs);
    k_smfin<<<1, 256, 0, stream>>>(pairs, 256, scal + 2);
    seg_b();
  };

  layer((const float*)x, W1, b1, an1, ae1, [&] {
    k_segB<1><<<(N + 3) / 4, 256, 0, stream>>>(he, ea, na, scal, csrc_has, off_has,
                                               (void*)y1b, N);
  });
  layer((const u16*)y1b, W2, b2, an2, ae2, [&] {
    k_segB<0><<<(N + 3) / 4, 256, 0, stream>>>(he, ea, na, scal, csrc_has, off_has,
                                               d_out, N);
  });
}

// Round 10
// 470.959 us; speedup vs baseline: 3.9396x; 1.0225x over previous
//
#include <hip/hip_runtime.h>
#include <hip/hip_bf16.h>
#include <math.h>
#include <type_traits>

// HGAT: 2-layer hypergraph attention. N nodes, M hyperedges, E incidence edges, D=128.
// R10: tail shaving. segA (64us x2) is at the random-gather floor — untouched.
// - softmax1 fused into fc: deg-factorized (sum deg*exp(na)), per-block online pair ->
//   pairs[782] -> smfin. k_sm1e dropped (x2). deg from in_src slices in the ONE k_hpart2
//   launch (grid 32x9); reduction folded into k_scan1d (y=2 -> raw sums).
// - fc occupancy 2->3 blocks/CU (LDS 35KB).
// - colscan/stage/place direction pairs merged via blockIdx.y (separate ebufs in partial).
// 20 dispatches (was 25). Scatter v3 (R8), MFMA fc (R4), bf16 rows (R3) unchanged.

typedef unsigned int u32;
typedef unsigned short u16;
typedef u16 u16x8 __attribute__((ext_vector_type(8)));
typedef short bf16x8 __attribute__((ext_vector_type(8)));
typedef float f32x4 __attribute__((ext_vector_type(4)));

#define NCONST 100000
#define MCONST 20000
#define ECONST 1600000
#define HCH2 32768  // histogram chunk (ints) = 128KB LDS
#define HBC 32      // blocks per chunk
#define NCH_N 4     // ceil(N / HCH2)

#define PBLK 256        // partition blocks (1 chunk each)
#define PT 6250         // edges per partition chunk (E/PBLK)
#define SHB_IN 6        // coarse bucket shift, in-direction (bucket = 64 segs)
#define NBK_IN 313      // ceil(M / 64)
#define SRCB_IN 17      // src bits (in_src < 100000 < 2^17)
#define SHB_HAS 8       // coarse bucket shift, has-direction (bucket = 256 segs)
#define NBK_HAS 391     // ceil(N / 256)
#define SRCB_HAS 15     // src bits (has_src < 20000 < 2^15)

__device__ __forceinline__ u16 f2bf(float f) {  // RNE
  u32 u = __float_as_uint(f);
  u += 0x7FFFu + ((u >> 16) & 1u);
  return (u16)(u >> 16);
}
__device__ __forceinline__ float bf2f(u16 b) {
  return __uint_as_float(((u32)b) << 16);
}

// ---------------- histograms: one launch, LDS-private, no global atomics ----------------
// grid (HBC, 9): y=0 -> in_dst (M, 1 chunk); y=1..4 -> has_dst chunks; y=5..8 -> in_src.
__global__ __launch_bounds__(256) void k_hpart2(const int* __restrict__ in_dst,
                                                const int* __restrict__ has_dst,
                                                const int* __restrict__ in_src,
                                                int* __restrict__ partial) {
  __shared__ int hc[HCH2];
  int y = blockIdx.y;
  const int* __restrict__ arr = (y == 0) ? in_dst : (y <= 4 ? has_dst : in_src);
  int lo = (y == 0) ? 0 : (y <= 4 ? (y - 1) * HCH2 : (y - 5) * HCH2);
  for (int i = threadIdx.x; i < HCH2; i += 256) hc[i] = 0;
  __syncthreads();
  int stride = gridDim.x * 256;
  int n4 = ECONST >> 2;
  const int4* a4 = (const int4*)arr;
  for (int i = blockIdx.x * 256 + threadIdx.x; i < n4; i += stride) {
    int4 v = a4[i];
    u32 a = (u32)(v.x - lo), b = (u32)(v.y - lo), c = (u32)(v.z - lo), d = (u32)(v.w - lo);
    if (a < HCH2) atomicAdd(&hc[a], 1);
    if (b < HCH2) atomicAdd(&hc[b], 1);
    if (c < HCH2) atomicAdd(&hc[c], 1);
    if (d < HCH2) atomicAdd(&hc[d], 1);
  }
  __syncthreads();
  int* out = partial + ((size_t)y * HBC + blockIdx.x) * HCH2;
  for (int i = threadIdx.x; i < HCH2; i += 256) out[i] = hc[i];
}

// ---------------- scans: y=0 -> off_in (M), y=1 -> off_has (N), y=2 -> deg (raw sums)
__global__ void k_scan1d(const int* __restrict__ partial, int nM, int nN,
                         int* __restrict__ off_in, int* __restrict__ off_has,
                         int* __restrict__ deg, int* __restrict__ bsum) {
  __shared__ int sd[256];
  int y = blockIdx.y;
  int n = y ? nN : nM;
  int rowbase = (y == 0) ? 0 : (y == 1 ? 1 : 5);
  int t = threadIdx.x;
  int base = blockIdx.x * 1024 + t * 4;
  int v[4];
#pragma unroll
  for (int k = 0; k < 4; ++k) {
    int j = base + k;
    int s = 0;
    if (j < n) {
      int chunk = j >> 15;
      int jl = j & (HCH2 - 1);
      const int* p = partial + ((size_t)(rowbase + chunk) * HBC) * HCH2 + jl;
#pragma unroll
      for (int b = 0; b < HBC; ++b) s += p[(size_t)b * HCH2];
    }
    v[k] = s;
  }
  if (y == 2) {
#pragma unroll
    for (int k = 0; k < 4; ++k)
      if (base + k < n) deg[base + k] = v[k];
    return;
  }
  int* off = y ? off_has : off_in;
  int* bs = bsum + y * 128;
  v[1] += v[0]; v[2] += v[1]; v[3] += v[2];
  int tot = v[3];
  sd[t] = tot;
  __syncthreads();
  for (int o = 1; o < 256; o <<= 1) {
    int x = (t >= o) ? sd[t - o] : 0;
    __syncthreads();
    sd[t] += x;
    __syncthreads();
  }
  int excl = sd[t] - tot;
#pragma unroll
  for (int k = 0; k < 4; ++k)
    if (base + k < n) off[base + k + 1] = v[k] + excl;
  if (t == 255) bs[blockIdx.x] = sd[255];
}

__global__ void k_scan2d(int* __restrict__ bsum, int nbM, int nbN) {
  __shared__ int sd[256];
  int* bs = bsum + blockIdx.x * 128;
  int nb = blockIdx.x ? nbN : nbM;
  int t = threadIdx.x;
  int v = (t < nb) ? bs[t] : 0;
  sd[t] = v;
  __syncthreads();
  for (int o = 1; o < 256; o <<= 1) {
    int x = (t >= o) ? sd[t - o] : 0;
    __syncthreads();
    sd[t] += x;
    __syncthreads();
  }
  if (t < nb) bs[t] = sd[t] - v;  // exclusive
}

__global__ void k_scan3d(int* __restrict__ off_in, int* __restrict__ off_has,
                         const int* __restrict__ bsum, int nM, int nN) {
  int y = blockIdx.y;
  int* off = y ? off_has : off_in;
  const int* bs = bsum + y * 128;
  int n = y ? nN : nM;
  int i = blockIdx.x * blockDim.x + threadIdx.x;
  int st = gridDim.x * blockDim.x;
  if (blockIdx.x == 0 && threadIdx.x == 0) off[0] = 0;
  for (; i < n; i += st) off[i + 1] += bs[i >> 10];
}

// ---------------- scatter v3: atomic-free LDS-staged partition ----------------
__global__ __launch_bounds__(256) void k_coarse(const int* __restrict__ in_dst,
                                                const int* __restrict__ has_dst,
                                                int* __restrict__ bb_in,
                                                int* __restrict__ bb_has) {
  __shared__ int h1[NBK_IN];
  __shared__ int h2[NBK_HAS];
  for (int i = threadIdx.x; i < NBK_IN; i += 256) h1[i] = 0;
  for (int i = threadIdx.x; i < NBK_HAS; i += 256) h2[i] = 0;
  __syncthreads();
  int c0 = blockIdx.x * PT, c1 = min(c0 + PT, ECONST);
  for (int i = c0 + threadIdx.x; i < c1; i += 256) {
    atomicAdd(&h1[in_dst[i] >> SHB_IN], 1);
    atomicAdd(&h2[has_dst[i] >> SHB_HAS], 1);
  }
  __syncthreads();
  int* o1 = bb_in + (size_t)blockIdx.x * NBK_IN;
  for (int i = threadIdx.x; i < NBK_IN; i += 256) o1[i] = h1[i];
  int* o2 = bb_has + (size_t)blockIdx.x * NBK_HAS;
  for (int i = threadIdx.x; i < NBK_HAS; i += 256) o2[i] = h2[i];
}

template <int NBUK, int SHB>
__device__ __forceinline__ void colscan_body(int* __restrict__ bb,
                                             const int* __restrict__ off, int segs,
                                             int* sd) {
  int b = blockIdx.x;
  if (b >= NBUK) return;  // uniform per block
  int t = threadIdx.x;
  int v = bb[(size_t)t * NBUK + b];
  sd[t] = v;
  __syncthreads();
  for (int o = 1; o < 256; o <<= 1) {
    int x = (t >= o) ? sd[t - o] : 0;
    __syncthreads();
    sd[t] += x;
    __syncthreads();
  }
  bb[(size_t)t * NBUK + b] = sd[t] - v + off[min(b << SHB, segs)];
}

__global__ __launch_bounds__(256) void k_colscan2(int* __restrict__ bb_in,
                                                  const int* __restrict__ off_in,
                                                  int* __restrict__ bb_has,
                                                  const int* __restrict__ off_has) {
  __shared__ int sd[256];
  if (blockIdx.y == 0)
    colscan_body<NBK_IN, SHB_IN>(bb_in, off_in, MCONST, sd);
  else
    colscan_body<NBK_HAS, SHB_HAS>(bb_has, off_has, NCONST, sd);
}

template <int NBUK, int SHB, int SRCB>
__device__ __forceinline__ void stage_body(const int* __restrict__ dst,
                                           const int* __restrict__ srcv,
                                           const int* __restrict__ bb,
                                           int* __restrict__ ebuf, int* hist, int* loff,
                                           int* gbase, int* stg, int* sd) {
  int t = threadIdx.x;
  for (int i = t; i < NBUK; i += 256) hist[i] = 0;
  __syncthreads();
  int c0 = blockIdx.x * PT, c1 = min(c0 + PT, ECONST);
  for (int i = c0 + t; i < c1; i += 256) atomicAdd(&hist[dst[i] >> SHB], 1);
  __syncthreads();
  {
    int v0 = (2 * t < NBUK) ? hist[2 * t] : 0;
    int v1 = (2 * t + 1 < NBUK) ? hist[2 * t + 1] : 0;
    sd[t] = v0 + v1;
    __syncthreads();
    for (int o = 1; o < 256; o <<= 1) {
      int x = (t >= o) ? sd[t - o] : 0;
      __syncthreads();
      sd[t] += x;
      __syncthreads();
    }
    int excl = sd[t] - (v0 + v1);
    if (2 * t < NBUK) loff[2 * t] = excl;
    if (2 * t + 1 < NBUK) loff[2 * t + 1] = excl + v0;
  }
  __syncthreads();
  for (int i = t; i < NBUK; i += 256) {
    gbase[i] = bb[(size_t)blockIdx.x * NBUK + i];
    hist[i] = loff[i];  // cursor
  }
  __syncthreads();
  for (int i = c0 + t; i < c1; i += 256) {
    int d = dst[i], s = srcv[i];
    int b = d >> SHB;
    int r = atomicAdd(&hist[b], 1);
    stg[r] = (b << 23) | ((d & ((1 << SHB) - 1)) << SRCB) | s;
  }
  __syncthreads();
  int tot = c1 - c0;
  for (int i = t; i < tot; i += 256) {
    int v = stg[i];
    int b = ((u32)v) >> 23;
    ebuf[gbase[b] + (i - loff[b])] = v & ((1 << 23) - 1);
  }
}

__global__ __launch_bounds__(256) void k_stage2(
    const int* __restrict__ in_dst, const int* __restrict__ in_src,
    const int* __restrict__ bb_in, int* __restrict__ ebuf_in,
    const int* __restrict__ has_dst, const int* __restrict__ has_src,
    const int* __restrict__ bb_has, int* __restrict__ ebuf_has) {
  __shared__ int hist[NBK_HAS];
  __shared__ int loff[NBK_HAS];
  __shared__ int gbase[NBK_HAS];
  __shared__ int stg[PT];
  __shared__ int sd[256];
  if (blockIdx.y == 0)
    stage_body<NBK_IN, SHB_IN, SRCB_IN>(in_dst, in_src, bb_in, ebuf_in, hist, loff, gbase,
                                        stg, sd);
  else
    stage_body<NBK_HAS, SHB_HAS, SRCB_HAS>(has_dst, has_src, bb_has, ebuf_has, hist, loff,
                                           gbase, stg, sd);
}

template <int SHB, int SRCB>
__device__ __forceinline__ void place_body(const int* __restrict__ off, int segs,
                                           const int* __restrict__ ebuf,
                                           int* __restrict__ csrc, int* cur) {
  const int NSEG = 1 << SHB;
  int seg0 = blockIdx.x << SHB;
  if (seg0 >= segs) return;  // uniform per block
  int segN = min(seg0 + NSEG, segs);
  for (int i = threadIdx.x; i < segN - seg0; i += 256) cur[i] = off[seg0 + i];
  __syncthreads();
  int start = off[seg0], end = off[segN];
  for (int i = start + threadIdx.x; i < end; i += 256) {
    int v = ebuf[i];
    int dloc = ((u32)v) >> SRCB;
    int pos = atomicAdd(&cur[dloc], 1);
    csrc[pos] = v & ((1 << SRCB) - 1);
  }
}

__global__ __launch_bounds__(256) void k_place2(
    const int* __restrict__ off_in, const int* __restrict__ ebuf_in,
    int* __restrict__ csrc_in, const int* __restrict__ off_has,
    const int* __restrict__ ebuf_has, int* __restrict__ csrc_has) {
  __shared__ int cur[256];
  if (blockIdx.y == 0)
    place_body<SHB_IN, SRCB_IN>(off_in, MCONST, ebuf_in, csrc_in, cur);
  else
    place_body<SHB_HAS, SRCB_HAS>(off_has, NCONST, ebuf_has, csrc_has, cur);
}

// ---------------- online softmax merge helper ----------------
__device__ __forceinline__ void merge_write(float m, float s, float2* __restrict__ pairs) {
  for (int o = 1; o < 64; o <<= 1) {
    float om = __shfl_xor(m, o, 64), os = __shfl_xor(s, o, 64);
    float nm = fmaxf(m, om);
    s = s * __expf(m - nm) + os * __expf(om - nm);
    m = nm;
  }
  __shared__ float sm[4], ss[4];
  int t = threadIdx.x;
  if ((t & 63) == 0) { sm[t >> 6] = m; ss[t >> 6] = s; }
  __syncthreads();
  if (t == 0) {
    for (int k = 1; k < 4; ++k) {
      float nm = fmaxf(m, sm[k]);
      s = s * __expf(m - nm) + ss[k] * __expf(sm[k] - nm);
      m = nm;
    }
    pairs[blockIdx.x] = make_float2(m, s);
  }
}

// ---------------- FC: h = x@W + b (bf16 out), na = h@an, fused softmax1 pair ------------
// IT = float (layer 1) or u16 (layer 2, bf16 bits direct). Emits per-block online
// (max, sum deg*exp) pair for the factorized global softmax over n_attn[in_src].
template <typename IT>
__global__ __launch_bounds__(256, 3) void k_fc(
    const IT* __restrict__ x, const float* __restrict__ W,
    const float* __restrict__ bias, const float* __restrict__ an,
    const int* __restrict__ deg, u16* __restrict__ h, float* __restrict__ na,
    float2* __restrict__ pairs, int nrows) {
  __shared__ __align__(16) u16 sWT[128 * 136];
  __shared__ float sNa[128];
  int tid = threadIdx.x;
  int lane = tid & 63, w = tid >> 6;
  int cl = lane & 15, qg = lane >> 4;

  for (int i = tid * 4; i < 16384; i += 1024) {
    float4 v = *(const float4*)(W + i);
    int k = i >> 7, j = i & 127;
    sWT[(j + 0) * 136 + k] = f2bf(v.x);
    sWT[(j + 1) * 136 + k] = f2bf(v.y);
    sWT[(j + 2) * 136 + k] = f2bf(v.z);
    sWT[(j + 3) * 136 + k] = f2bf(v.w);
  }

  float anv[8], bv[8];
#pragma unroll
  for (int t = 0; t < 8; ++t) {
    anv[t] = an[t * 16 + cl];
    bv[t] = bias[t * 16 + cl];
  }

  int rbase = blockIdx.x * 128 + w * 32;
  bf16x8 afr[2][4];
#pragma unroll
  for (int g = 0; g < 2; ++g) {
    int r = rbase + g * 16 + cl;
    int rc = min(r, nrows - 1);
    const IT* xp = x + (size_t)rc * 128 + qg * 8;
#pragma unroll
    for (int s = 0; s < 4; ++s) {
      if constexpr (sizeof(IT) == 4) {
        float4 u0 = *(const float4*)(xp + s * 32);
        float4 u1 = *(const float4*)(xp + s * 32 + 4);
        bf16x8 a;
        a[0] = (short)f2bf(u0.x); a[1] = (short)f2bf(u0.y);
        a[2] = (short)f2bf(u0.z); a[3] = (short)f2bf(u0.w);
        a[4] = (short)f2bf(u1.x); a[5] = (short)f2bf(u1.y);
        a[6] = (short)f2bf(u1.z); a[7] = (short)f2bf(u1.w);
        afr[g][s] = a;
      } else {
        afr[g][s] = *(const bf16x8*)(xp + s * 32);
      }
    }
  }
  __syncthreads();

  f32x4 acc[2][8];
#pragma unroll
  for (int g = 0; g < 2; ++g)
#pragma unroll
    for (int t = 0; t < 8; ++t) {
      acc[g][t][0] = 0.f; acc[g][t][1] = 0.f; acc[g][t][2] = 0.f; acc[g][t][3] = 0.f;
    }

#pragma unroll
  for (int t = 0; t < 8; ++t) {
    bf16x8 bfrg[4];
    const u16* bp = sWT + (t * 16 + cl) * 136 + qg * 8;
#pragma unroll
    for (int s = 0; s < 4; ++s) bfrg[s] = *(const bf16x8*)(bp + s * 32);
#pragma unroll
    for (int s = 0; s < 4; ++s) {
#pragma unroll
      for (int g = 0; g < 2; ++g)
        acc[g][t] = __builtin_amdgcn_mfma_f32_16x16x32_bf16(afr[g][s], bfrg[s], acc[g][t],
                                                            0, 0, 0);
    }
  }

  float pa[2][4];
#pragma unroll
  for (int g = 0; g < 2; ++g)
#pragma unroll
    for (int reg = 0; reg < 4; ++reg) pa[g][reg] = 0.f;
#pragma unroll
  for (int g = 0; g < 2; ++g)
#pragma unroll
    for (int t = 0; t < 8; ++t)
#pragma unroll
      for (int reg = 0; reg < 4; ++reg)
        pa[g][reg] = fmaf(acc[g][t][reg] + bv[t], anv[t], pa[g][reg]);
#pragma unroll
  for (int g = 0; g < 2; ++g)
#pragma unroll
    for (int reg = 0; reg < 4; ++reg) {
      float v = pa[g][reg];
      v += __shfl_xor(v, 1, 64);
      v += __shfl_xor(v, 2, 64);
      v += __shfl_xor(v, 4, 64);
      v += __shfl_xor(v, 8, 64);
      pa[g][reg] = v;
    }
  if (cl == 0) {
#pragma unroll
    for (int g = 0; g < 2; ++g)
#pragma unroll
      for (int reg = 0; reg < 4; ++reg) {
        int r = rbase + g * 16 + qg * 4 + reg;
        int lidx = w * 32 + g * 16 + qg * 4 + reg;
        if (r < nrows) {
          na[r] = pa[g][reg];
          sNa[lidx] = pa[g][reg];
        }
      }
  }

  __syncthreads();
  u16* st = sWT + w * 32 * 136;
#pragma unroll
  for (int g = 0; g < 2; ++g)
#pragma unroll
    for (int t = 0; t < 8; ++t)
#pragma unroll
      for (int reg = 0; reg < 4; ++reg)
        st[(g * 16 + qg * 4 + reg) * 136 + t * 16 + cl] = f2bf(acc[g][t][reg] + bv[t]);
#pragma unroll
  for (int it = 0; it < 8; ++it) {
    int idx = it * 64 + lane;
    int row = idx >> 4, c = idx & 15;
    u16x8 v = *(const u16x8*)(st + row * 136 + c * 8);
    int r = rbase + row;
    if (r < nrows) *(u16x8*)(h + (size_t)r * 128 + c * 8) = v;
  }

  // fused softmax1 partial: per-node (m = na, s = deg); block online-merge.
  float m1 = -1e30f, s1 = 0.f;
  if (tid < 128) {
    int r = blockIdx.x * 128 + tid;
    if (r < nrows) {
      int d = deg[r];
      if (d > 0) { m1 = sNa[tid]; s1 = (float)d; }
    }
  }
  merge_write(m1, s1, pairs);
}

// ---------------- softmax2 single online pass over E ----------------
__global__ void k_sm2(const float* __restrict__ ea, const float* __restrict__ na,
                      const int* __restrict__ hs, const int* __restrict__ hd, int n,
                      float2* __restrict__ pairs) {
  float m = -1e30f, s = 0.f;
  int i = blockIdx.x * blockDim.x + threadIdx.x;
  int st = gridDim.x * blockDim.x;
  for (; i < n; i += st) {
    float xv = ea[hs[i]] + na[hd[i]];
    if (xv > m) { s *= __expf(m - xv); m = xv; }
    s += __expf(xv - m);
  }
  merge_write(m, s, pairs);
}

__global__ void k_smfin(const float2* __restrict__ pairs, int nb, float* __restrict__ out) {
  int t = threadIdx.x;
  float m = -1e30f, s = 0.f;
  for (int i = t; i < nb; i += 256) {
    float2 pr = pairs[i];
    float nm = fmaxf(m, pr.x);
    s = s * __expf(m - nm) + pr.y * __expf(pr.x - nm);
    m = nm;
  }
  for (int o = 1; o < 64; o <<= 1) {
    float om = __shfl_xor(m, o, 64), os = __shfl_xor(s, o, 64);
    float nm = fmaxf(m, om);
    s = s * __expf(m - nm) + os * __expf(om - nm);
    m = nm;
  }
  __shared__ float sm[4], ss[4];
  if ((t & 63) == 0) { sm[t >> 6] = m; ss[t >> 6] = s; }
  __syncthreads();
  if (t == 0) {
    for (int k = 1; k < 4; ++k) {
      float nm = fmaxf(m, sm[k]);
      s = s * __expf(m - nm) + ss[k] * __expf(sm[k] - nm);
      m = nm;
    }
    out[0] = m;
    out[1] = s;
  }
}

// ---------------- segment sums (one wave/segment, 16B/lane, 4 edges/iter) ----------------
__global__ __launch_bounds__(256) void k_segA(
    const u16* __restrict__ h, const float* __restrict__ na,
    const float* __restrict__ scal, const int* __restrict__ csrc,
    const int* __restrict__ off, const float* __restrict__ ae, u16* __restrict__ he,
    float* __restrict__ ea, int m_count) {
  int wid = (blockIdx.x << 2) + (threadIdx.x >> 6);
  if (wid >= m_count) return;
  float mx = scal[0];
  float iz = 1.0f / scal[1];
  int lane = threadIdx.x & 63;
  int sub = lane >> 4, cl = lane & 15;
  int s = off[wid], t = off[wid + 1];
  float ax[8];
#pragma unroll
  for (int j = 0; j < 8; ++j) ax[j] = 0.f;
  for (int i = s + sub; i < t; i += 4) {
    int sr = csrc[i];
    float ww = __expf(na[sr] - mx) * iz;
    u16x8 v = *(const u16x8*)(h + (size_t)sr * 128 + cl * 8);
#pragma unroll
    for (int j = 0; j < 8; ++j) ax[j] = fmaf(ww, bf2f(v[j]), ax[j]);
  }
#pragma unroll
  for (int j = 0; j < 8; ++j) {
    ax[j] += __shfl_xor(ax[j], 16, 64);
    ax[j] += __shfl_xor(ax[j], 32, 64);
  }
  float4 a0 = *(const float4*)(ae + cl * 8);
  float4 a1 = *(const float4*)(ae + cl * 8 + 4);
  float pa = ax[0] * a0.x + ax[1] * a0.y + ax[2] * a0.z + ax[3] * a0.w +
             ax[4] * a1.x + ax[5] * a1.y + ax[6] * a1.z + ax[7] * a1.w;
  pa += __shfl_xor(pa, 1, 64);
  pa += __shfl_xor(pa, 2, 64);
  pa += __shfl_xor(pa, 4, 64);
  pa += __shfl_xor(pa, 8, 64);
  if (sub == 0) {
    u16x8 o;
#pragma unroll
    for (int j = 0; j < 8; ++j) o[j] = f2bf(ax[j]);
    *(u16x8*)(he + (size_t)wid * 128 + cl * 8) = o;
    if (cl == 0) ea[wid] = pa;
  }
}

template <int L1>
__global__ __launch_bounds__(256) void k_segB(
    const u16* __restrict__ he, const float* __restrict__ ea,
    const float* __restrict__ na, const float* __restrict__ scal,
    const int* __restrict__ csrc, const int* __restrict__ off,
    void* __restrict__ yout, int n_count) {
  int wid = (blockIdx.x << 2) + (threadIdx.x >> 6);
  if (wid >= n_count) return;
  float mx2 = scal[2];
  float iz2 = 1.0f / scal[3];
  int lane = threadIdx.x & 63;
  int sub = lane >> 4, cl = lane & 15;
  float nav = na[wid];
  int s = off[wid], t = off[wid + 1];
  float ax[8];
#pragma unroll
  for (int j = 0; j < 8; ++j) ax[j] = 0.f;
  for (int i = s + sub; i < t; i += 4) {
    int sr = csrc[i];
    float c = __expf(ea[sr] + nav - mx2) * iz2;
    u16x8 v = *(const u16x8*)(he + (size_t)sr * 128 + cl * 8);
#pragma unroll
    for (int j = 0; j < 8; ++j) ax[j] = fmaf(c, bf2f(v[j]), ax[j]);
  }
#pragma unroll
  for (int j = 0; j < 8; ++j) {
    ax[j] += __shfl_xor(ax[j], 16, 64);
    ax[j] += __shfl_xor(ax[j], 32, 64);
    if (L1) ax[j] = fmaxf(ax[j], 0.f);
  }
  if (sub == 0) {
    if (L1) {
      u16x8 o;
#pragma unroll
      for (int j = 0; j < 8; ++j) o[j] = f2bf(ax[j]);
      *(u16x8*)((u16*)yout + (size_t)wid * 128 + cl * 8) = o;
    } else {
      float4 A = make_float4(ax[0], ax[1], ax[2], ax[3]);
      float4 B = make_float4(ax[4], ax[5], ax[6], ax[7]);
      float* y = (float*)yout;
      *(float4*)(y + (size_t)wid * 128 + cl * 8) = A;
      *(float4*)(y + (size_t)wid * 128 + cl * 8 + 4) = B;
    }
  }
}

// ---------------- host ----------------
extern "C" void kernel_launch(void* const* d_in, const int* in_sizes, int n_in,
                              void* d_out, int out_size, void* d_ws, size_t ws_size,
                              hipStream_t stream) {
  const int N = NCONST, M = MCONST, E = ECONST;
  const float* x = (const float*)d_in[0];
  const int* in_src = (const int*)d_in[1];
  const int* in_dst = (const int*)d_in[2];
  const int* has_src = (const int*)d_in[3];
  const int* has_dst = (const int*)d_in[4];
  const float* W1 = (const float*)d_in[5];
  const float* b1 = (const float*)d_in[6];
  const float* an1 = (const float*)d_in[7];
  const float* ae1 = (const float*)d_in[8];
  const float* W2 = (const float*)d_in[9];
  const float* b2 = (const float*)d_in[10];
  const float* an2 = (const float*)d_in[11];
  const float* ae2 = (const float*)d_in[12];

  const size_t PARTIAL_BYTES = (size_t)9 * HBC * HCH2 * 4;  // 37.7 MB

  char* p = (char*)d_ws;
  auto alloc = [&](size_t bytes) {
    char* q = p;
    p += (bytes + 255) & ~(size_t)255;
    return q;
  };
  u16* h = (u16*)alloc((size_t)N * 128 * 2);
  u16* he = (u16*)alloc((size_t)M * 128 * 2);
  float* na = (float*)alloc((size_t)N * 4);
  float* ea = (float*)alloc((size_t)M * 4);
  int* deg = (int*)alloc((size_t)N * 4);
  int* off_in = (int*)alloc((size_t)(M + 1) * 4);
  int* off_has = (int*)alloc((size_t)(N + 1) * 4);
  int* csrc_in = (int*)alloc((size_t)E * 4);
  int* csrc_has = (int*)alloc((size_t)E * 4);
  int* partial = (int*)alloc(PARTIAL_BYTES);  // unions with ebufs (disjoint lifetime)
  int* ebuf_in = partial;
  int* ebuf_has = partial + ECONST;
  int* bb_in = (int*)alloc((size_t)PBLK * NBK_IN * 4);
  int* bb_has = (int*)alloc((size_t)PBLK * NBK_HAS * 4);
  int* bsum = (int*)alloc(256 * 4);
  float2* pairs = (float2*)alloc(1024 * 8);
  float* scal = (float*)alloc(64);
  if ((size_t)(p - (char*)d_ws) > ws_size) return;  // insufficient workspace

  u16* y1b = (u16*)d_out;  // layer-1 bf16 output staged in d_out bytes (fc2-only reader;
                           // overwritten by final fp32 result in segB<0>)

  // histograms (one launch) + merged scans (+ deg reduction as y=2)
  k_hpart2<<<dim3(HBC, 9), 256, 0, stream>>>(in_dst, has_dst, in_src, partial);
  int nbM = (M + 1023) / 1024, nbN = (N + 1023) / 1024;
  k_scan1d<<<dim3(nbN, 3), 256, 0, stream>>>(partial, M, N, off_in, off_has, deg, bsum);
  k_scan2d<<<2, 256, 0, stream>>>(bsum, nbM, nbN);
  k_scan3d<<<dim3(512, 2), 256, 0, stream>>>(off_in, off_has, bsum, M, N);

  // scatter v3 (atomic-free partition), directions merged via blockIdx.y
  k_coarse<<<PBLK, 256, 0, stream>>>(in_dst, has_dst, bb_in, bb_has);
  k_colscan2<<<dim3(NBK_HAS, 2), 256, 0, stream>>>(bb_in, off_in, bb_has, off_has);
  k_stage2<<<dim3(PBLK, 2), 256, 0, stream>>>(in_dst, in_src, bb_in, ebuf_in, has_dst,
                                              has_src, bb_has, ebuf_has);
  k_place2<<<dim3(NBK_HAS, 2), 256, 0, stream>>>(off_in, ebuf_in, csrc_in, off_has,
                                                 ebuf_has, csrc_has);

  const int FCB = (N + 127) / 128;  // 782 fc blocks = pairs count
  auto layer = [&](auto xin, const float* W, const float* b, const float* an_,
                   const float* ae_, auto seg_b) {
    using IT = typename std::remove_const<
        typename std::remove_pointer<decltype(xin)>::type>::type;
    k_fc<IT><<<FCB, 256, 0, stream>>>(xin, W, b, an_, deg, h, na, pairs, N);
    k_smfin<<<1, 256, 0, stream>>>(pairs, FCB, scal);
    k_segA<<<(M + 3) / 4, 256, 0, stream>>>(h, na, scal, csrc_in, off_in, ae_, he, ea, M);
    k_sm2<<<256, 256, 0, stream>>>(ea, na, has_src, has_dst, E, pairs);
    k_smfin<<<1, 256, 0, stream>>>(pairs, 256, scal + 2);
    seg_b();
  };

  layer((const float*)x, W1, b1, an1, ae1, [&] {
    k_segB<1><<<(N + 3) / 4, 256, 0, stream>>>(he, ea, na, scal, csrc_has, off_has,
                                               (void*)y1b, N);
  });
  layer((const u16*)y1b, W2, b2, an2, ae2, [&] {
    k_segB<0><<<(N + 3) / 4, 256, 0, stream>>>(he, ea, na, scal, csrc_has, off_has,
                                               d_out, N);
  });
}